// Round 1
// baseline (365.723 us; speedup 1.0000x reference)
//
#include <hip/hip_runtime.h>
#include <hip/hip_bf16.h>
#include <stdint.h>

#define D_MODEL 1024
#define NHEADS 16
#define HD 64
#define BB 4
#define TT 2048
#define MM (BB*TT)          // 8192 rows
#define NQKV (3*D_MODEL)    // 3072
#define KK D_MODEL          // 1024

typedef __attribute__((ext_vector_type(4))) float f32x4;
typedef __attribute__((ext_vector_type(8))) short bf16x8;

__device__ __forceinline__ unsigned short f2bf(float x){
    union { __hip_bfloat16 h; unsigned short u; } c;
    c.h = __float2bfloat16(x);
    return c.u;
}

__device__ __forceinline__ void gload_lds16(const void* g, void* l){
    __builtin_amdgcn_global_load_lds(
        (const __attribute__((address_space(1))) unsigned int*)g,
        (__attribute__((address_space(3))) unsigned int*)l,
        16, 0, 0);
}

// ---------------- cast fp32 -> bf16, vectorized ----------------
__global__ void cast_kernel(const float* __restrict__ in,
                            unsigned short* __restrict__ out, int n4){
    int i = blockIdx.x * blockDim.x + threadIdx.x;
    if (i >= n4) return;
    float4 v = reinterpret_cast<const float4*>(in)[i];
    ushort4 o;
    o.x = f2bf(v.x); o.y = f2bf(v.y); o.z = f2bf(v.z); o.w = f2bf(v.w);
    reinterpret_cast<ushort4*>(out)[i] = o;
}

// ---------------- QKV projection GEMM ----------------
// A: x_bf16 [8192][1024] row-major (K-contig)
// Bw: w_qkv_bf16 [3072][1024] row-major == B^T (K-contig)
// out: q,k [BH][T][64] bf16 ; v transposed [BH][64][T] bf16 ; bias added
__global__ __launch_bounds__(256) void gemm_qkv(
    const unsigned short* __restrict__ A, const unsigned short* __restrict__ Bw,
    const float* __restrict__ bias,
    unsigned short* __restrict__ qb, unsigned short* __restrict__ kb,
    unsigned short* __restrict__ vtb)
{
    __shared__ unsigned short As[128*32];
    __shared__ unsigned short Bs[128*32];
    const int tiles_n = NQKV/128;                 // 24
    int bm = (blockIdx.x / tiles_n) * 128;
    int bn = (blockIdx.x % tiles_n) * 128;
    int tid = threadIdx.x;
    int w = tid >> 6, l = tid & 63;
    int wr = (w >> 1) * 64, wc = (w & 1) * 64;
    int lr = l & 15, hi = l >> 4;

    f32x4 acc[4][4] = {};

    int srow = tid >> 2;            // 0..63
    int scol = (tid & 3) * 8;       // ushort offset
    const unsigned short* Ap = A + (size_t)(bm + srow) * KK + scol;
    const unsigned short* Bp = Bw + (size_t)(bn + srow) * KK + scol;
    char* AsB = (char*)As + w * 1024;
    char* BsB = (char*)Bs + w * 1024;

    for (int k0 = 0; k0 < KK; k0 += 32) {
        __syncthreads();
        gload_lds16(Ap + k0,           AsB);
        gload_lds16(Ap + 64*KK + k0,   AsB + 4096);
        gload_lds16(Bp + k0,           BsB);
        gload_lds16(Bp + 64*KK + k0,   BsB + 4096);
        __syncthreads();
        bf16x8 af[4], bfr[4];
        #pragma unroll
        for (int m = 0; m < 4; m++)
            af[m] = *reinterpret_cast<const bf16x8*>(&As[(wr + m*16 + lr)*32 + hi*8]);
        #pragma unroll
        for (int n = 0; n < 4; n++)
            bfr[n] = *reinterpret_cast<const bf16x8*>(&Bs[(wc + n*16 + lr)*32 + hi*8]);
        #pragma unroll
        for (int m = 0; m < 4; m++)
            #pragma unroll
            for (int n = 0; n < 4; n++)
                acc[m][n] = __builtin_amdgcn_mfma_f32_16x16x32_bf16(af[m], bfr[n], acc[m][n], 0, 0, 0);
    }

    // epilogue: C row = (hi*4 + r) + m*16 + wr (token dim), col = lr + n*16 + wc (feature dim)
    #pragma unroll
    for (int m = 0; m < 4; m++) {
        int gm = bm + wr + m*16 + hi*4;       // +r
        int b  = gm >> 11;                    // /2048
        int t  = gm & 2047;
        #pragma unroll
        for (int n = 0; n < 4; n++) {
            int gn = bn + wc + n*16 + lr;
            float bv = bias[gn];
            int sec = gn >> 10;               // 0=Q 1=K 2=V
            int nn  = gn & 1023;
            int h = nn >> 6, d = nn & 63;
            int bh = b * NHEADS + h;
            if (sec == 2) {
                ushort4 pk;
                pk.x = f2bf(acc[m][n][0] + bv);
                pk.y = f2bf(acc[m][n][1] + bv);
                pk.z = f2bf(acc[m][n][2] + bv);
                pk.w = f2bf(acc[m][n][3] + bv);
                *reinterpret_cast<ushort4*>(&vtb[((size_t)bh*HD + d)*TT + t]) = pk;
            } else {
                unsigned short* dst = (sec == 0) ? qb : kb;
                #pragma unroll
                for (int r = 0; r < 4; r++)
                    dst[((size_t)bh*TT + t + r)*HD + d] = f2bf(acc[m][n][r] + bv);
            }
        }
    }
}

// ---------------- causal flash attention ----------------
// grid: (B*H, T/64); 4 waves, wave w owns q rows [qt*64+w*16, +16)
__global__ __launch_bounds__(256) void attn_kernel(
    const unsigned short* __restrict__ qb, const unsigned short* __restrict__ kb,
    const unsigned short* __restrict__ vtb, unsigned short* __restrict__ ao)
{
    __shared__ unsigned short Pl[4][16*64];
    int bh = blockIdx.x;
    int qt = blockIdx.y;
    int tid = threadIdx.x;
    int w = tid >> 6, l = tid & 63;
    int lr = l & 15, hi = l >> 4;
    int qrow = qt*64 + w*16;

    const unsigned short* Qp = qb + ((size_t)bh*TT + qrow) * HD;
    bf16x8 qf0 = *reinterpret_cast<const bf16x8*>(Qp + lr*HD + hi*8);
    bf16x8 qf1 = *reinterpret_cast<const bf16x8*>(Qp + lr*HD + 32 + hi*8);
    const unsigned short* Kp0 = kb + (size_t)bh*TT*HD;
    const unsigned short* Vp  = vtb + (size_t)bh*HD*TT;

    float mS[4], lSum[4];
    f32x4 o[4] = {};
    #pragma unroll
    for (int r = 0; r < 4; r++) { mS[r] = -3e38f; lSum[r] = 0.f; }
    const float sc = 0.125f * 1.4426950408889634f;   // 1/sqrt(64) * log2(e)

    for (int kt = 0; kt <= qt; ++kt) {
        int kbase = kt * 64;
        const unsigned short* Kp = Kp0 + (size_t)kbase * HD;
        f32x4 s[4] = {};
        #pragma unroll
        for (int n = 0; n < 4; n++) {
            bf16x8 kf0 = *reinterpret_cast<const bf16x8*>(Kp + (n*16 + lr)*HD + hi*8);
            bf16x8 kf1 = *reinterpret_cast<const bf16x8*>(Kp + (n*16 + lr)*HD + 32 + hi*8);
            s[n] = __builtin_amdgcn_mfma_f32_16x16x32_bf16(qf0, kf0, s[n], 0, 0, 0);
            s[n] = __builtin_amdgcn_mfma_f32_16x16x32_bf16(qf1, kf1, s[n], 0, 0, 0);
        }
        // scale (into log2 domain) + causal mask on diagonal tile
        #pragma unroll
        for (int n = 0; n < 4; n++)
            #pragma unroll
            for (int r = 0; r < 4; r++)
                s[n][r] *= sc;
        if (kt == qt) {
            #pragma unroll
            for (int n = 0; n < 4; n++)
                #pragma unroll
                for (int r = 0; r < 4; r++)
                    if (n*16 + lr > w*16 + hi*4 + r) s[n][r] = -3e38f;
        }
        // row max across 4 frags then across the 16-lane column group
        float rm[4];
        #pragma unroll
        for (int r = 0; r < 4; r++) {
            rm[r] = fmaxf(fmaxf(s[0][r], s[1][r]), fmaxf(s[2][r], s[3][r]));
            #pragma unroll
            for (int msk = 1; msk < 16; msk <<= 1)
                rm[r] = fmaxf(rm[r], __shfl_xor(rm[r], msk, 64));
        }
        #pragma unroll
        for (int r = 0; r < 4; r++) {
            float newm = fmaxf(mS[r], rm[r]);
            float al = exp2f(mS[r] - newm);
            mS[r] = newm;
            float rs = 0.f;
            #pragma unroll
            for (int n = 0; n < 4; n++) {
                float pv = exp2f(s[n][r] - newm);
                rs += pv;
                Pl[w][(hi*4 + r)*64 + n*16 + lr] = f2bf(pv);
            }
            #pragma unroll
            for (int msk = 1; msk < 16; msk <<= 1)
                rs += __shfl_xor(rs, msk, 64);
            lSum[r] = lSum[r]*al + rs;
            o[0][r] *= al; o[1][r] *= al; o[2][r] *= al; o[3][r] *= al;
        }
        // PV: A = P [16 q x 64 k] from LDS, B = V^T rows (K-contig)
        #pragma unroll
        for (int st = 0; st < 2; st++) {
            bf16x8 pa = *reinterpret_cast<const bf16x8*>(&Pl[w][lr*64 + st*32 + hi*8]);
            #pragma unroll
            for (int n = 0; n < 4; n++) {
                bf16x8 vf = *reinterpret_cast<const bf16x8*>(
                    Vp + (size_t)(n*16 + lr)*TT + kbase + st*32 + hi*8);
                o[n] = __builtin_amdgcn_mfma_f32_16x16x32_bf16(pa, vf, o[n], 0, 0, 0);
            }
        }
    }
    // normalize + store [B,T,D] bf16
    int b = bh >> 4, h = bh & 15;
    #pragma unroll
    for (int n = 0; n < 4; n++)
        #pragma unroll
        for (int r = 0; r < 4; r++) {
            float val = o[n][r] / lSum[r];
            int t = qrow + hi*4 + r;
            ao[((size_t)b*TT + t)*D_MODEL + h*HD + n*16 + lr] = f2bf(val);
        }
}

// ---------------- output projection GEMM ----------------
__global__ __launch_bounds__(256) void gemm_out(
    const unsigned short* __restrict__ A, const unsigned short* __restrict__ Bw,
    const float* __restrict__ bias, float* __restrict__ out)
{
    __shared__ unsigned short As[128*32];
    __shared__ unsigned short Bs[128*32];
    const int tiles_n = D_MODEL/128;              // 8
    int bm = (blockIdx.x / tiles_n) * 128;
    int bn = (blockIdx.x % tiles_n) * 128;
    int tid = threadIdx.x;
    int w = tid >> 6, l = tid & 63;
    int wr = (w >> 1) * 64, wc = (w & 1) * 64;
    int lr = l & 15, hi = l >> 4;

    f32x4 acc[4][4] = {};

    int srow = tid >> 2;
    int scol = (tid & 3) * 8;
    const unsigned short* Ap = A + (size_t)(bm + srow) * KK + scol;
    const unsigned short* Bp = Bw + (size_t)(bn + srow) * KK + scol;
    char* AsB = (char*)As + w * 1024;
    char* BsB = (char*)Bs + w * 1024;

    for (int k0 = 0; k0 < KK; k0 += 32) {
        __syncthreads();
        gload_lds16(Ap + k0,          AsB);
        gload_lds16(Ap + 64*KK + k0,  AsB + 4096);
        gload_lds16(Bp + k0,          BsB);
        gload_lds16(Bp + 64*KK + k0,  BsB + 4096);
        __syncthreads();
        bf16x8 af[4], bfr[4];
        #pragma unroll
        for (int m = 0; m < 4; m++)
            af[m] = *reinterpret_cast<const bf16x8*>(&As[(wr + m*16 + lr)*32 + hi*8]);
        #pragma unroll
        for (int n = 0; n < 4; n++)
            bfr[n] = *reinterpret_cast<const bf16x8*>(&Bs[(wc + n*16 + lr)*32 + hi*8]);
        #pragma unroll
        for (int m = 0; m < 4; m++)
            #pragma unroll
            for (int n = 0; n < 4; n++)
                acc[m][n] = __builtin_amdgcn_mfma_f32_16x16x32_bf16(af[m], bfr[n], acc[m][n], 0, 0, 0);
    }

    #pragma unroll
    for (int m = 0; m < 4; m++) {
        int gm = bm + wr + m*16 + hi*4;
        #pragma unroll
        for (int n = 0; n < 4; n++) {
            int gn = bn + wc + n*16 + lr;
            float bv = bias[gn];
            #pragma unroll
            for (int r = 0; r < 4; r++)
                out[(size_t)(gm + r)*D_MODEL + gn] = acc[m][n][r] + bv;
        }
    }
}

extern "C" void kernel_launch(void* const* d_in, const int* in_sizes, int n_in,
                              void* d_out, int out_size, void* d_ws, size_t ws_size,
                              hipStream_t stream) {
    const float* x     = (const float*)d_in[0];
    const float* w_qkv = (const float*)d_in[1];
    const float* b_qkv = (const float*)d_in[2];
    const float* w_out = (const float*)d_in[3];
    const float* b_out = (const float*)d_in[4];
    float* out = (float*)d_out;

    char* ws = (char*)d_ws;
    unsigned short* xbf   = (unsigned short*)(ws);                         // 16 MB
    unsigned short* wqkvb = (unsigned short*)(ws + (size_t)16777216);      // 6 MB
    unsigned short* woutb = (unsigned short*)(ws + (size_t)23068672);      // 2 MB
    unsigned short* qb    = (unsigned short*)(ws + (size_t)25165824);      // 16 MB
    unsigned short* kb    = (unsigned short*)(ws + (size_t)41943040);      // 16 MB
    unsigned short* vtb   = (unsigned short*)(ws + (size_t)58720256);      // 16 MB
    unsigned short* aob   = xbf;  // alias: x_bf16 is dead after gemm_qkv

    cast_kernel<<<(MM*KK/4)/256,       256, 0, stream>>>(x,     xbf,   MM*KK/4);
    cast_kernel<<<(NQKV*KK/4)/256,     256, 0, stream>>>(w_qkv, wqkvb, NQKV*KK/4);
    cast_kernel<<<(D_MODEL*D_MODEL/4)/256, 256, 0, stream>>>(w_out, woutb, D_MODEL*D_MODEL/4);

    gemm_qkv<<<(MM/128)*(NQKV/128), 256, 0, stream>>>(xbf, wqkvb, b_qkv, qb, kb, vtb);
    attn_kernel<<<dim3(BB*NHEADS, TT/64), 256, 0, stream>>>(qb, kb, vtb, aob);
    gemm_out<<<(MM/128)*(D_MODEL/128), 256, 0, stream>>>(aob, woutb, b_out, out);
}

// Round 2
// 184.056 us; speedup vs baseline: 1.9870x; 1.9870x over previous
//
#include <hip/hip_runtime.h>
#include <hip/hip_bf16.h>
#include <stdint.h>

#define D_MODEL 1024
#define NHEADS 16
#define HD 64
#define BB 4
#define TT 2048
#define MM (BB*TT)          // 8192 rows
#define NQKV (3*D_MODEL)    // 3072
#define KK D_MODEL          // 1024

typedef __attribute__((ext_vector_type(4))) float f32x4;
typedef __attribute__((ext_vector_type(8))) short bf16x8;

__device__ __forceinline__ unsigned short f2bf(float x){
    union { __hip_bfloat16 h; unsigned short u; } c;
    c.h = __float2bfloat16(x);
    return c.u;
}

__device__ __forceinline__ void gload_lds16(const void* g, void* l){
    __builtin_amdgcn_global_load_lds(
        (const __attribute__((address_space(1))) unsigned int*)g,
        (__attribute__((address_space(3))) unsigned int*)l,
        16, 0, 0);
}

// ---------------- cast fp32 -> bf16, vectorized ----------------
__global__ void cast_kernel(const float* __restrict__ in,
                            unsigned short* __restrict__ out, int n4){
    int i = blockIdx.x * blockDim.x + threadIdx.x;
    if (i >= n4) return;
    float4 v = reinterpret_cast<const float4*>(in)[i];
    ushort4 o;
    o.x = f2bf(v.x); o.y = f2bf(v.y); o.z = f2bf(v.z); o.w = f2bf(v.w);
    reinterpret_cast<ushort4*>(out)[i] = o;
}

// ---------------- QKV projection GEMM ----------------
__global__ __launch_bounds__(256) void gemm_qkv(
    const unsigned short* __restrict__ A, const unsigned short* __restrict__ Bw,
    const float* __restrict__ bias,
    unsigned short* __restrict__ qb, unsigned short* __restrict__ kb,
    unsigned short* __restrict__ vtb)
{
    __shared__ alignas(16) unsigned short As[128*32];
    __shared__ alignas(16) unsigned short Bs[128*32];
    const int tiles_n = NQKV/128;                 // 24
    int bm = (blockIdx.x / tiles_n) * 128;
    int bn = (blockIdx.x % tiles_n) * 128;
    int tid = threadIdx.x;
    int w = tid >> 6, l = tid & 63;
    int wr = (w >> 1) * 64, wc = (w & 1) * 64;
    int lr = l & 15, hi = l >> 4;

    f32x4 acc[4][4] = {};

    int srow = tid >> 2;            // 0..63
    int scol = (tid & 3) * 8;       // ushort offset
    const unsigned short* Ap = A + (size_t)(bm + srow) * KK + scol;
    const unsigned short* Bp = Bw + (size_t)(bn + srow) * KK + scol;
    char* AsB = (char*)As + w * 1024;
    char* BsB = (char*)Bs + w * 1024;

    for (int k0 = 0; k0 < KK; k0 += 32) {
        __syncthreads();
        gload_lds16(Ap + k0,           AsB);
        gload_lds16(Ap + 64*KK + k0,   AsB + 4096);
        gload_lds16(Bp + k0,           BsB);
        gload_lds16(Bp + 64*KK + k0,   BsB + 4096);
        __syncthreads();
        bf16x8 af[4], bfr[4];
        #pragma unroll
        for (int m = 0; m < 4; m++)
            af[m] = *reinterpret_cast<const bf16x8*>(&As[(wr + m*16 + lr)*32 + hi*8]);
        #pragma unroll
        for (int n = 0; n < 4; n++)
            bfr[n] = *reinterpret_cast<const bf16x8*>(&Bs[(wc + n*16 + lr)*32 + hi*8]);
        #pragma unroll
        for (int m = 0; m < 4; m++)
            #pragma unroll
            for (int n = 0; n < 4; n++)
                acc[m][n] = __builtin_amdgcn_mfma_f32_16x16x32_bf16(af[m], bfr[n], acc[m][n], 0, 0, 0);
    }

    #pragma unroll
    for (int m = 0; m < 4; m++) {
        int gm = bm + wr + m*16 + hi*4;       // +r
        int b  = gm >> 11;
        int t  = gm & 2047;
        #pragma unroll
        for (int n = 0; n < 4; n++) {
            int gn = bn + wc + n*16 + lr;
            float bv = bias[gn];
            int sec = gn >> 10;               // 0=Q 1=K 2=V
            int nn  = gn & 1023;
            int h = nn >> 6, d = nn & 63;
            int bh = b * NHEADS + h;
            if (sec == 2) {
                ushort4 pk;
                pk.x = f2bf(acc[m][n][0] + bv);
                pk.y = f2bf(acc[m][n][1] + bv);
                pk.z = f2bf(acc[m][n][2] + bv);
                pk.w = f2bf(acc[m][n][3] + bv);
                *reinterpret_cast<ushort4*>(&vtb[((size_t)bh*HD + d)*TT + t]) = pk;
            } else {
                unsigned short* dst = (sec == 0) ? qb : kb;
                #pragma unroll
                for (int r = 0; r < 4; r++)
                    dst[((size_t)bh*TT + t + r)*HD + d] = f2bf(acc[m][n][r] + bv);
            }
        }
    }
}

// ---------------- causal flash attention v2 ----------------
// grid (bh, 16); 8 waves/block; Q tile 128 rows, wave w owns rows [w*16,+16)
// Swapped QK^T: s = mfma(K, Q) -> lane (lr,hi) holds S[k=kb+n*16+hi*4+r][q=qrow+lr]
__global__ __launch_bounds__(512) void attn_kernel(
    const unsigned short* __restrict__ qb, const unsigned short* __restrict__ kb,
    const unsigned short* __restrict__ vtb, unsigned short* __restrict__ ao)
{
    __shared__ alignas(16) unsigned short Kb[2][64*64];
    __shared__ alignas(16) unsigned short Vb[2][64*64];
    __shared__ alignas(16) unsigned short Pl[8][16*64];

    const int bh = blockIdx.x;
    const int qt = (gridDim.y - 1) - blockIdx.y;   // big tiles first
    const int tid = threadIdx.x;
    const int w = tid >> 6, l = tid & 63;
    const int lr = l & 15, hi = l >> 4;

    const int qbase = qt * 128;
    const int qrow  = qbase + w*16;
    const int ktmax = 2*qt + 1;

    const unsigned short* Qp = qb + ((size_t)bh*TT + qrow) * HD;
    bf16x8 qf0 = *reinterpret_cast<const bf16x8*>(Qp + lr*HD + hi*8);
    bf16x8 qf1 = *reinterpret_cast<const bf16x8*>(Qp + lr*HD + 32 + hi*8);

    const unsigned short* Kg = kb  + (size_t)bh*TT*HD;
    const unsigned short* Vg = vtb + (size_t)bh*HD*TT;

    // staging: wave w loads rows [w*8, w*8+8) of the 64-row tile.
    // LDS is linear [row][col16]; source col is pre-swizzled so that
    // LDS[row][c] == G[row][c ^ (row&7)]  (read applies same XOR).
    const int srow = w*8 + (l >> 3);          // 0..63
    const int sc16 = (l & 7) ^ (srow & 7);
    char* KbL[2] = { (char*)&Kb[0][0] + w*1024, (char*)&Kb[1][0] + w*1024 };
    char* VbL[2] = { (char*)&Vb[0][0] + w*1024, (char*)&Vb[1][0] + w*1024 };

    // prologue: stage kt=0 into buf 0
    gload_lds16(Kg + (size_t)srow*HD + sc16*8, KbL[0]);
    gload_lds16(Vg + (size_t)srow*TT + sc16*8, VbL[0]);
    __syncthreads();

    float mS = -3e38f, lS = 0.f;
    f32x4 o[4] = {};
    const float sc = 0.125f * 1.4426950408889634f;   // 1/sqrt(64) * log2(e)
    const int qg = qrow + lr;
    const int swp = (lr & 7) << 4;
    char* Pw = (char*)&Pl[w][0];

    int cur = 0;
    for (int kt = 0; kt <= ktmax; ++kt) {
        const int kbase = kt*64;
        if (kt < ktmax) {   // prefetch next tile into other buffer
            int knext = kbase + 64;
            gload_lds16(Kg + (size_t)(knext + srow)*HD + sc16*8, KbL[cur^1]);
            gload_lds16(Vg + (size_t)srow*TT + knext + sc16*8,   VbL[cur^1]);
        }
        if (kbase <= qrow + 15) {   // wave not fully masked
            const char* Kl = (const char*)&Kb[cur][0];
            const char* Vl = (const char*)&Vb[cur][0];
            f32x4 s[4] = {};
            #pragma unroll
            for (int n = 0; n < 4; n++) {
                int rb = (n*16 + lr) * 128;
                bf16x8 kf0 = *reinterpret_cast<const bf16x8*>(Kl + rb + (( 0 + hi*16) ^ swp));
                bf16x8 kf1 = *reinterpret_cast<const bf16x8*>(Kl + rb + ((64 + hi*16) ^ swp));
                s[n] = __builtin_amdgcn_mfma_f32_16x16x32_bf16(kf0, qf0, s[n], 0, 0, 0);
                s[n] = __builtin_amdgcn_mfma_f32_16x16x32_bf16(kf1, qf1, s[n], 0, 0, 0);
            }
            if (kbase + 63 > qrow) {   // diagonal region: apply causal mask
                #pragma unroll
                for (int n = 0; n < 4; n++)
                    #pragma unroll
                    for (int r = 0; r < 4; r++)
                        if (kbase + n*16 + hi*4 + r > qg) s[n][r] = -3e38f;
            }
            // row max: 15 in-lane + cross-hi reduce
            float rm = s[0][0];
            #pragma unroll
            for (int n = 0; n < 4; n++)
                #pragma unroll
                for (int r = 0; r < 4; r++) rm = fmaxf(rm, s[n][r]);
            rm = fmaxf(rm, __shfl_xor(rm, 16, 64));
            rm = fmaxf(rm, __shfl_xor(rm, 32, 64));
            float newm = fmaxf(mS, rm);
            float al = exp2f(sc * (mS - newm));
            mS = newm;
            const float c0 = sc * newm;
            float rs = 0.f;
            #pragma unroll
            for (int n = 0; n < 4; n++) {
                float p0 = exp2f(fmaf(s[n][0], sc, -c0));
                float p1 = exp2f(fmaf(s[n][1], sc, -c0));
                float p2 = exp2f(fmaf(s[n][2], sc, -c0));
                float p3 = exp2f(fmaf(s[n][3], sc, -c0));
                rs += (p0 + p1) + (p2 + p3);
                ushort4 u;
                u.x = f2bf(p0); u.y = f2bf(p1); u.z = f2bf(p2); u.w = f2bf(p3);
                *reinterpret_cast<ushort4*>(Pw + (lr*128 + ((n*32 + hi*8) ^ swp))) = u;
            }
            rs += __shfl_xor(rs, 16, 64);
            rs += __shfl_xor(rs, 32, 64);
            lS = lS * al + rs;
            // rescale O (rows q = hi*4+r; al lives in lane q)
            #pragma unroll
            for (int r = 0; r < 4; r++) {
                float alr = __shfl(al, hi*4 + r, 64);
                o[0][r] *= alr; o[1][r] *= alr; o[2][r] *= alr; o[3][r] *= alr;
            }
            // PV: A = P[q][k] (swizzled per-wave LDS), B = V^T rows (d, K-contig)
            bf16x8 pa0 = *reinterpret_cast<const bf16x8*>(Pw + (lr*128 + (( 0 + hi*16) ^ swp)));
            bf16x8 pa1 = *reinterpret_cast<const bf16x8*>(Pw + (lr*128 + ((64 + hi*16) ^ swp)));
            #pragma unroll
            for (int nd = 0; nd < 4; nd++) {
                int rb = (nd*16 + lr) * 128;
                bf16x8 vf0 = *reinterpret_cast<const bf16x8*>(Vl + rb + (( 0 + hi*16) ^ swp));
                bf16x8 vf1 = *reinterpret_cast<const bf16x8*>(Vl + rb + ((64 + hi*16) ^ swp));
                o[nd] = __builtin_amdgcn_mfma_f32_16x16x32_bf16(pa0, vf0, o[nd], 0, 0, 0);
                o[nd] = __builtin_amdgcn_mfma_f32_16x16x32_bf16(pa1, vf1, o[nd], 0, 0, 0);
            }
        }
        __syncthreads();
        cur ^= 1;
    }

    // epilogue: O[q=hi*4+r][d=nd*16+lr], lS lives in lane q
    float inv = 1.0f / lS;
    int b = bh >> 4, h = bh & 15;
    #pragma unroll
    for (int r = 0; r < 4; r++) {
        float invr = __shfl(inv, hi*4 + r, 64);
        int t = qrow + hi*4 + r;
        #pragma unroll
        for (int nd = 0; nd < 4; nd++) {
            float val = o[nd][r] * invr;
            ao[((size_t)b*TT + t)*D_MODEL + h*HD + nd*16 + lr] = f2bf(val);
        }
    }
}

// ---------------- output projection GEMM ----------------
__global__ __launch_bounds__(256) void gemm_out(
    const unsigned short* __restrict__ A, const unsigned short* __restrict__ Bw,
    const float* __restrict__ bias, float* __restrict__ out)
{
    __shared__ alignas(16) unsigned short As[128*32];
    __shared__ alignas(16) unsigned short Bs[128*32];
    const int tiles_n = D_MODEL/128;              // 8
    int bm = (blockIdx.x / tiles_n) * 128;
    int bn = (blockIdx.x % tiles_n) * 128;
    int tid = threadIdx.x;
    int w = tid >> 6, l = tid & 63;
    int wr = (w >> 1) * 64, wc = (w & 1) * 64;
    int lr = l & 15, hi = l >> 4;

    f32x4 acc[4][4] = {};

    int srow = tid >> 2;
    int scol = (tid & 3) * 8;
    const unsigned short* Ap = A + (size_t)(bm + srow) * KK + scol;
    const unsigned short* Bp = Bw + (size_t)(bn + srow) * KK + scol;
    char* AsB = (char*)As + w * 1024;
    char* BsB = (char*)Bs + w * 1024;

    for (int k0 = 0; k0 < KK; k0 += 32) {
        __syncthreads();
        gload_lds16(Ap + k0,          AsB);
        gload_lds16(Ap + 64*KK + k0,  AsB + 4096);
        gload_lds16(Bp + k0,          BsB);
        gload_lds16(Bp + 64*KK + k0,  BsB + 4096);
        __syncthreads();
        bf16x8 af[4], bfr[4];
        #pragma unroll
        for (int m = 0; m < 4; m++)
            af[m] = *reinterpret_cast<const bf16x8*>(&As[(wr + m*16 + lr)*32 + hi*8]);
        #pragma unroll
        for (int n = 0; n < 4; n++)
            bfr[n] = *reinterpret_cast<const bf16x8*>(&Bs[(wc + n*16 + lr)*32 + hi*8]);
        #pragma unroll
        for (int m = 0; m < 4; m++)
            #pragma unroll
            for (int n = 0; n < 4; n++)
                acc[m][n] = __builtin_amdgcn_mfma_f32_16x16x32_bf16(af[m], bfr[n], acc[m][n], 0, 0, 0);
    }

    #pragma unroll
    for (int m = 0; m < 4; m++) {
        int gm = bm + wr + m*16 + hi*4;
        #pragma unroll
        for (int n = 0; n < 4; n++) {
            int gn = bn + wc + n*16 + lr;
            float bv = bias[gn];
            #pragma unroll
            for (int r = 0; r < 4; r++)
                out[(size_t)(gm + r)*D_MODEL + gn] = acc[m][n][r] + bv;
        }
    }
}

extern "C" void kernel_launch(void* const* d_in, const int* in_sizes, int n_in,
                              void* d_out, int out_size, void* d_ws, size_t ws_size,
                              hipStream_t stream) {
    const float* x     = (const float*)d_in[0];
    const float* w_qkv = (const float*)d_in[1];
    const float* b_qkv = (const float*)d_in[2];
    const float* w_out = (const float*)d_in[3];
    const float* b_out = (const float*)d_in[4];
    float* out = (float*)d_out;

    char* ws = (char*)d_ws;
    unsigned short* xbf   = (unsigned short*)(ws);                         // 16 MB
    unsigned short* wqkvb = (unsigned short*)(ws + (size_t)16777216);      // 6 MB
    unsigned short* woutb = (unsigned short*)(ws + (size_t)23068672);      // 2 MB
    unsigned short* qb    = (unsigned short*)(ws + (size_t)25165824);      // 16 MB
    unsigned short* kb    = (unsigned short*)(ws + (size_t)41943040);      // 16 MB
    unsigned short* vtb   = (unsigned short*)(ws + (size_t)58720256);      // 16 MB
    unsigned short* aob   = xbf;  // alias: x_bf16 dead after gemm_qkv

    cast_kernel<<<(MM*KK/4)/256,       256, 0, stream>>>(x,     xbf,   MM*KK/4);
    cast_kernel<<<(NQKV*KK/4)/256,     256, 0, stream>>>(w_qkv, wqkvb, NQKV*KK/4);
    cast_kernel<<<(D_MODEL*D_MODEL/4)/256, 256, 0, stream>>>(w_out, woutb, D_MODEL*D_MODEL/4);

    gemm_qkv<<<(MM/128)*(NQKV/128), 256, 0, stream>>>(xbf, wqkvb, b_qkv, qb, kb, vtb);
    attn_kernel<<<dim3(BB*NHEADS, TT/128), 512, 0, stream>>>(qb, kb, vtb, aob);
    gemm_out<<<(MM/128)*(D_MODEL/128), 256, 0, stream>>>(aob, woutb, b_out, out);
}

// Round 3
// 179.876 us; speedup vs baseline: 2.0332x; 1.0232x over previous
//
#include <hip/hip_runtime.h>
#include <hip/hip_bf16.h>
#include <stdint.h>

#define D_MODEL 1024
#define NHEADS 16
#define HD 64
#define BB 4
#define TT 2048
#define MM (BB*TT)          // 8192 rows
#define NQKV (3*D_MODEL)    // 3072
#define KK D_MODEL          // 1024

typedef __attribute__((ext_vector_type(4))) float f32x4;
typedef __attribute__((ext_vector_type(8))) short bf16x8;

__device__ __forceinline__ unsigned short f2bf(float x){
    union { __hip_bfloat16 h; unsigned short u; } c;
    c.h = __float2bfloat16(x);
    return c.u;
}

__device__ __forceinline__ void gload_lds16(const void* g, void* l){
    __builtin_amdgcn_global_load_lds(
        (const __attribute__((address_space(1))) unsigned int*)g,
        (__attribute__((address_space(3))) unsigned int*)l,
        16, 0, 0);
}

// ---------------- fused fp32 -> bf16 casts ----------------
#define N4_X  (MM*KK/4)
#define N4_WQ (NQKV*KK/4)
#define N4_WO (D_MODEL*D_MODEL/4)
__global__ void cast3_kernel(const float* __restrict__ x, const float* __restrict__ wq,
                             const float* __restrict__ wo,
                             unsigned short* __restrict__ xb, unsigned short* __restrict__ wqb,
                             unsigned short* __restrict__ wob){
    int i = blockIdx.x * blockDim.x + threadIdx.x;
    const float* src; unsigned short* dst; int j;
    if (i < N4_X)              { src = x;  dst = xb;  j = i; }
    else if (i < N4_X + N4_WQ) { src = wq; dst = wqb; j = i - N4_X; }
    else                       { src = wo; dst = wob; j = i - N4_X - N4_WQ; }
    float4 v = reinterpret_cast<const float4*>(src)[j];
    ushort4 o;
    o.x = f2bf(v.x); o.y = f2bf(v.y); o.z = f2bf(v.z); o.w = f2bf(v.w);
    reinterpret_cast<ushort4*>(dst)[j] = o;
}

// ---------------- QKV projection GEMM (double-buffered 2-phase) ----------------
__global__ __launch_bounds__(256) void gemm_qkv(
    const unsigned short* __restrict__ A, const unsigned short* __restrict__ Bw,
    const float* __restrict__ bias,
    unsigned short* __restrict__ qb, unsigned short* __restrict__ kb,
    unsigned short* __restrict__ vtb)
{
    __shared__ alignas(16) unsigned short As[2][128*32];
    __shared__ alignas(16) unsigned short Bs[2][128*32];
    const int tiles_n = NQKV/128;                 // 24
    int nwg = gridDim.x;
    int orig = blockIdx.x;
    int bid = (orig & 7) * (nwg >> 3) + (orig >> 3);   // bijective: nwg%8==0
    int bm = (bid / tiles_n) * 128;
    int bn = (bid % tiles_n) * 128;
    int tid = threadIdx.x;
    int w = tid >> 6, l = tid & 63;
    int wr = (w >> 1) * 64, wc = (w & 1) * 64;
    int lr = l & 15, hi = l >> 4;

    f32x4 acc[4][4] = {};

    int srow = tid >> 2;            // 0..63
    int scol = (tid & 3) * 8;       // ushort offset
    const unsigned short* Ap = A + (size_t)(bm + srow) * KK + scol;
    const unsigned short* Bp = Bw + (size_t)(bn + srow) * KK + scol;

    // prologue: stage k0=0 into buf 0
    {
        char* AsB = (char*)&As[0][0] + w*1024;
        char* BsB = (char*)&Bs[0][0] + w*1024;
        gload_lds16(Ap,           AsB);
        gload_lds16(Ap + 64*KK,   AsB + 4096);
        gload_lds16(Bp,           BsB);
        gload_lds16(Bp + 64*KK,   BsB + 4096);
    }
    __syncthreads();

    int cur = 0;
    for (int k0 = 0; k0 < KK; k0 += 32) {
        if (k0 + 32 < KK) {
            char* AsB = (cur ? (char*)&As[0][0] : (char*)&As[1][0]) + w*1024;
            char* BsB = (cur ? (char*)&Bs[0][0] : (char*)&Bs[1][0]) + w*1024;
            gload_lds16(Ap + k0 + 32,          AsB);
            gload_lds16(Ap + 64*KK + k0 + 32,  AsB + 4096);
            gload_lds16(Bp + k0 + 32,          BsB);
            gload_lds16(Bp + 64*KK + k0 + 32,  BsB + 4096);
        }
        const unsigned short* Ab = cur ? &As[1][0] : &As[0][0];
        const unsigned short* Bb = cur ? &Bs[1][0] : &Bs[0][0];
        bf16x8 af[4], bfr[4];
        #pragma unroll
        for (int m = 0; m < 4; m++)
            af[m] = *reinterpret_cast<const bf16x8*>(&Ab[(wr + m*16 + lr)*32 + hi*8]);
        #pragma unroll
        for (int n = 0; n < 4; n++)
            bfr[n] = *reinterpret_cast<const bf16x8*>(&Bb[(wc + n*16 + lr)*32 + hi*8]);
        #pragma unroll
        for (int m = 0; m < 4; m++)
            #pragma unroll
            for (int n = 0; n < 4; n++)
                acc[m][n] = __builtin_amdgcn_mfma_f32_16x16x32_bf16(af[m], bfr[n], acc[m][n], 0, 0, 0);
        __syncthreads();
        cur ^= 1;
    }

    #pragma unroll
    for (int m = 0; m < 4; m++) {
        int gm = bm + wr + m*16 + hi*4;       // +r
        int b  = gm >> 11;
        int t  = gm & 2047;
        #pragma unroll
        for (int n = 0; n < 4; n++) {
            int gn = bn + wc + n*16 + lr;
            float bv = bias[gn];
            int sec = gn >> 10;               // 0=Q 1=K 2=V
            int nn  = gn & 1023;
            int h = nn >> 6, d = nn & 63;
            int bh = b * NHEADS + h;
            if (sec == 2) {
                ushort4 pk;
                pk.x = f2bf(acc[m][n][0] + bv);
                pk.y = f2bf(acc[m][n][1] + bv);
                pk.z = f2bf(acc[m][n][2] + bv);
                pk.w = f2bf(acc[m][n][3] + bv);
                *reinterpret_cast<ushort4*>(&vtb[((size_t)bh*HD + d)*TT + t]) = pk;
            } else {
                unsigned short* dst = (sec == 0) ? qb : kb;
                #pragma unroll
                for (int r = 0; r < 4; r++)
                    dst[((size_t)bh*TT + t + r)*HD + d] = f2bf(acc[m][n][r] + bv);
            }
        }
    }
}

// ---------------- causal flash attention v3 ----------------
// grid (bh, 16); 8 waves/block; Q tile 128 rows, wave w owns rows [w*16,+16)
// Swapped QK^T: s = mfma(K, Q) -> lane (lr,hi) holds S[k=kb+n*16+hi*4+r][q=qrow+lr]
__global__ __launch_bounds__(512) void attn_kernel(
    const unsigned short* __restrict__ qb, const unsigned short* __restrict__ kb,
    const unsigned short* __restrict__ vtb, unsigned short* __restrict__ ao)
{
    __shared__ alignas(16) unsigned short Kb[2][64*64];
    __shared__ alignas(16) unsigned short Vb[2][64*64];
    __shared__ alignas(16) unsigned short Pl[8][16*64];

    const int bh = blockIdx.x;
    const int qt = (gridDim.y - 1) - blockIdx.y;   // big tiles first
    const int tid = threadIdx.x;
    const int w = tid >> 6, l = tid & 63;
    const int lr = l & 15, hi = l >> 4;

    const int qbase = qt * 128;
    const int qrow  = qbase + w*16;
    const int ktmax = 2*qt + 1;

    const unsigned short* Qp = qb + ((size_t)bh*TT + qrow) * HD;
    bf16x8 qf0 = *reinterpret_cast<const bf16x8*>(Qp + lr*HD + hi*8);
    bf16x8 qf1 = *reinterpret_cast<const bf16x8*>(Qp + lr*HD + 32 + hi*8);

    const unsigned short* Kg = kb  + (size_t)bh*TT*HD;
    const unsigned short* Vg = vtb + (size_t)bh*HD*TT;

    // staging: wave w loads rows [w*8, w*8+8) of the 64-row tile.
    // LDS[row][c] == G[row][c ^ (row&7)]  (read applies same XOR on 16B cols)
    const int srow = w*8 + (l >> 3);          // 0..63
    const int sc16 = (l & 7) ^ (srow & 7);
    char* KbL0 = (char*)&Kb[0][0] + w*1024;
    char* KbL1 = (char*)&Kb[1][0] + w*1024;
    char* VbL0 = (char*)&Vb[0][0] + w*1024;
    char* VbL1 = (char*)&Vb[1][0] + w*1024;

    gload_lds16(Kg + (size_t)srow*HD + sc16*8, KbL0);
    gload_lds16(Vg + (size_t)srow*TT + sc16*8, VbL0);
    __syncthreads();

    float mS = -3e38f, lS = 0.f;
    f32x4 o[4] = {};
    const float sc = 0.125f * 1.4426950408889634f;   // 1/sqrt(64) * log2(e)
    const float THR = 8.0f / sc;                      // defer-max threshold (raw units)
    const int qg = qrow + lr;
    const int swp = (lr & 7) << 4;
    char* Pw = (char*)&Pl[w][0];

    int cur = 0;
    for (int kt = 0; kt <= ktmax; ++kt) {
        const int kbase = kt*64;
        if (kt < ktmax) {   // prefetch next tile into other buffer
            int knext = kbase + 64;
            char* kd = cur ? KbL0 : KbL1;
            char* vd = cur ? VbL0 : VbL1;
            gload_lds16(Kg + (size_t)(knext + srow)*HD + sc16*8, kd);
            gload_lds16(Vg + (size_t)srow*TT + knext + sc16*8,   vd);
        }
        if (kbase <= qrow + 15) {   // wave not fully masked
            const char* Kl = cur ? (const char*)&Kb[1][0] : (const char*)&Kb[0][0];
            const char* Vl = cur ? (const char*)&Vb[1][0] : (const char*)&Vb[0][0];
            f32x4 s[4] = {};
            __builtin_amdgcn_s_setprio(1);
            #pragma unroll
            for (int n = 0; n < 4; n++) {
                int rb = (n*16 + lr) * 128;
                bf16x8 kf0 = *reinterpret_cast<const bf16x8*>(Kl + rb + (( 0 + hi*16) ^ swp));
                bf16x8 kf1 = *reinterpret_cast<const bf16x8*>(Kl + rb + ((64 + hi*16) ^ swp));
                s[n] = __builtin_amdgcn_mfma_f32_16x16x32_bf16(kf0, qf0, s[n], 0, 0, 0);
                s[n] = __builtin_amdgcn_mfma_f32_16x16x32_bf16(kf1, qf1, s[n], 0, 0, 0);
            }
            __builtin_amdgcn_s_setprio(0);
            if (kbase + 63 > qrow) {   // diagonal region: causal mask
                #pragma unroll
                for (int n = 0; n < 4; n++)
                    #pragma unroll
                    for (int r = 0; r < 4; r++)
                        if (kbase + n*16 + hi*4 + r > qg) s[n][r] = -3e38f;
            }
            // row max: parallel tree (max3-fusable) + cross-hi reduce
            float t0 = fmaxf(fmaxf(s[0][0], s[0][1]), fmaxf(s[0][2], s[0][3]));
            float t1 = fmaxf(fmaxf(s[1][0], s[1][1]), fmaxf(s[1][2], s[1][3]));
            float t2 = fmaxf(fmaxf(s[2][0], s[2][1]), fmaxf(s[2][2], s[2][3]));
            float t3 = fmaxf(fmaxf(s[3][0], s[3][1]), fmaxf(s[3][2], s[3][3]));
            float rm = fmaxf(fmaxf(t0, t1), fmaxf(t2, t3));
            rm = fmaxf(rm, __shfl_xor(rm, 16, 64));
            rm = fmaxf(rm, __shfl_xor(rm, 32, 64));
            // defer-max: only rescale when the running max grows materially
            if (!__all(rm - mS <= THR)) {
                float newm = fmaxf(mS, rm);
                float al = exp2f(sc * (mS - newm));
                mS = newm;
                lS *= al;
                #pragma unroll
                for (int r = 0; r < 4; r++) {
                    float alr = __shfl(al, hi*4 + r, 64);
                    o[0][r] *= alr; o[1][r] *= alr; o[2][r] *= alr; o[3][r] *= alr;
                }
            }
            const float c0 = sc * mS;
            float rs = 0.f;
            #pragma unroll
            for (int n = 0; n < 4; n++) {
                float p0 = exp2f(fmaf(s[n][0], sc, -c0));
                float p1 = exp2f(fmaf(s[n][1], sc, -c0));
                float p2 = exp2f(fmaf(s[n][2], sc, -c0));
                float p3 = exp2f(fmaf(s[n][3], sc, -c0));
                rs += (p0 + p1) + (p2 + p3);
                ushort4 u;
                u.x = f2bf(p0); u.y = f2bf(p1); u.z = f2bf(p2); u.w = f2bf(p3);
                *reinterpret_cast<ushort4*>(Pw + (lr*128 + ((n*32 + hi*8) ^ swp))) = u;
            }
            rs += __shfl_xor(rs, 16, 64);
            rs += __shfl_xor(rs, 32, 64);
            lS += rs;
            // PV: A = P[q][k] (swizzled per-wave LDS), B = V^T rows (d, K-contig)
            bf16x8 pa0 = *reinterpret_cast<const bf16x8*>(Pw + (lr*128 + (( 0 + hi*16) ^ swp)));
            bf16x8 pa1 = *reinterpret_cast<const bf16x8*>(Pw + (lr*128 + ((64 + hi*16) ^ swp)));
            __builtin_amdgcn_s_setprio(1);
            #pragma unroll
            for (int nd = 0; nd < 4; nd++) {
                int rb = (nd*16 + lr) * 128;
                bf16x8 vf0 = *reinterpret_cast<const bf16x8*>(Vl + rb + (( 0 + hi*16) ^ swp));
                bf16x8 vf1 = *reinterpret_cast<const bf16x8*>(Vl + rb + ((64 + hi*16) ^ swp));
                o[nd] = __builtin_amdgcn_mfma_f32_16x16x32_bf16(pa0, vf0, o[nd], 0, 0, 0);
                o[nd] = __builtin_amdgcn_mfma_f32_16x16x32_bf16(pa1, vf1, o[nd], 0, 0, 0);
            }
            __builtin_amdgcn_s_setprio(0);
        }
        __syncthreads();
        cur ^= 1;
    }

    // epilogue: O[q=hi*4+r][d=nd*16+lr], lS lives in lane q
    float inv = 1.0f / lS;
    int b = bh >> 4, h = bh & 15;
    #pragma unroll
    for (int r = 0; r < 4; r++) {
        float invr = __shfl(inv, hi*4 + r, 64);
        int t = qrow + hi*4 + r;
        #pragma unroll
        for (int nd = 0; nd < 4; nd++) {
            float val = o[nd][r] * invr;
            ao[((size_t)b*TT + t)*D_MODEL + h*HD + nd*16 + lr] = f2bf(val);
        }
    }
}

// ---------------- output projection GEMM (double-buffered 2-phase) ----------------
__global__ __launch_bounds__(256) void gemm_out(
    const unsigned short* __restrict__ A, const unsigned short* __restrict__ Bw,
    const float* __restrict__ bias, float* __restrict__ out)
{
    __shared__ alignas(16) unsigned short As[2][128*32];
    __shared__ alignas(16) unsigned short Bs[2][128*32];
    const int tiles_n = D_MODEL/128;              // 8
    int nwg = gridDim.x;
    int orig = blockIdx.x;
    int bid = (orig & 7) * (nwg >> 3) + (orig >> 3);
    int bm = (bid / tiles_n) * 128;
    int bn = (bid % tiles_n) * 128;
    int tid = threadIdx.x;
    int w = tid >> 6, l = tid & 63;
    int wr = (w >> 1) * 64, wc = (w & 1) * 64;
    int lr = l & 15, hi = l >> 4;

    f32x4 acc[4][4] = {};

    int srow = tid >> 2;
    int scol = (tid & 3) * 8;
    const unsigned short* Ap = A + (size_t)(bm + srow) * KK + scol;
    const unsigned short* Bp = Bw + (size_t)(bn + srow) * KK + scol;

    {
        char* AsB = (char*)&As[0][0] + w*1024;
        char* BsB = (char*)&Bs[0][0] + w*1024;
        gload_lds16(Ap,           AsB);
        gload_lds16(Ap + 64*KK,   AsB + 4096);
        gload_lds16(Bp,           BsB);
        gload_lds16(Bp + 64*KK,   BsB + 4096);
    }
    __syncthreads();

    int cur = 0;
    for (int k0 = 0; k0 < KK; k0 += 32) {
        if (k0 + 32 < KK) {
            char* AsB = (cur ? (char*)&As[0][0] : (char*)&As[1][0]) + w*1024;
            char* BsB = (cur ? (char*)&Bs[0][0] : (char*)&Bs[1][0]) + w*1024;
            gload_lds16(Ap + k0 + 32,          AsB);
            gload_lds16(Ap + 64*KK + k0 + 32,  AsB + 4096);
            gload_lds16(Bp + k0 + 32,          BsB);
            gload_lds16(Bp + 64*KK + k0 + 32,  BsB + 4096);
        }
        const unsigned short* Ab = cur ? &As[1][0] : &As[0][0];
        const unsigned short* Bb = cur ? &Bs[1][0] : &Bs[0][0];
        bf16x8 af[4], bfr[4];
        #pragma unroll
        for (int m = 0; m < 4; m++)
            af[m] = *reinterpret_cast<const bf16x8*>(&Ab[(wr + m*16 + lr)*32 + hi*8]);
        #pragma unroll
        for (int n = 0; n < 4; n++)
            bfr[n] = *reinterpret_cast<const bf16x8*>(&Bb[(wc + n*16 + lr)*32 + hi*8]);
        #pragma unroll
        for (int m = 0; m < 4; m++)
            #pragma unroll
            for (int n = 0; n < 4; n++)
                acc[m][n] = __builtin_amdgcn_mfma_f32_16x16x32_bf16(af[m], bfr[n], acc[m][n], 0, 0, 0);
        __syncthreads();
        cur ^= 1;
    }

    #pragma unroll
    for (int m = 0; m < 4; m++) {
        int gm = bm + wr + m*16 + hi*4;
        #pragma unroll
        for (int n = 0; n < 4; n++) {
            int gn = bn + wc + n*16 + lr;
            float bv = bias[gn];
            #pragma unroll
            for (int r = 0; r < 4; r++)
                out[(size_t)(gm + r)*D_MODEL + gn] = acc[m][n][r] + bv;
        }
    }
}

extern "C" void kernel_launch(void* const* d_in, const int* in_sizes, int n_in,
                              void* d_out, int out_size, void* d_ws, size_t ws_size,
                              hipStream_t stream) {
    const float* x     = (const float*)d_in[0];
    const float* w_qkv = (const float*)d_in[1];
    const float* b_qkv = (const float*)d_in[2];
    const float* w_out = (const float*)d_in[3];
    const float* b_out = (const float*)d_in[4];
    float* out = (float*)d_out;

    char* ws = (char*)d_ws;
    unsigned short* xbf   = (unsigned short*)(ws);                         // 16 MB
    unsigned short* wqkvb = (unsigned short*)(ws + (size_t)16777216);      // 6 MB
    unsigned short* woutb = (unsigned short*)(ws + (size_t)23068672);      // 2 MB
    unsigned short* qb    = (unsigned short*)(ws + (size_t)25165824);      // 16 MB
    unsigned short* kb    = (unsigned short*)(ws + (size_t)41943040);      // 16 MB
    unsigned short* vtb   = (unsigned short*)(ws + (size_t)58720256);      // 16 MB
    unsigned short* aob   = xbf;  // alias: x_bf16 dead after gemm_qkv

    cast3_kernel<<<(N4_X + N4_WQ + N4_WO)/256, 256, 0, stream>>>(x, w_qkv, w_out, xbf, wqkvb, woutb);

    gemm_qkv<<<(MM/128)*(NQKV/128), 256, 0, stream>>>(xbf, wqkvb, b_qkv, qb, kb, vtb);
    attn_kernel<<<dim3(BB*NHEADS, TT/128), 512, 0, stream>>>(qb, kb, vtb, aob);
    gemm_out<<<(MM/128)*(D_MODEL/128), 256, 0, stream>>>(aob, woutb, b_out, out);
}

// Round 4
// 177.934 us; speedup vs baseline: 2.0554x; 1.0109x over previous
//
#include <hip/hip_runtime.h>
#include <hip/hip_bf16.h>
#include <stdint.h>

#define D_MODEL 1024
#define NHEADS 16
#define HD 64
#define BB 4
#define TT 2048
#define MM (BB*TT)          // 8192 rows
#define NQKV (3*D_MODEL)    // 3072
#define KK D_MODEL          // 1024

typedef __attribute__((ext_vector_type(4))) float f32x4;
typedef __attribute__((ext_vector_type(8))) short bf16x8;

__device__ __forceinline__ unsigned short f2bf(float x){
    union { __hip_bfloat16 h; unsigned short u; } c;
    c.h = __float2bfloat16(x);
    return c.u;
}

__device__ __forceinline__ void gload_lds16(const void* g, void* l){
    __builtin_amdgcn_global_load_lds(
        (const __attribute__((address_space(1))) unsigned int*)g,
        (__attribute__((address_space(3))) unsigned int*)l,
        16, 0, 0);
}

// ---------------- fused fp32 -> bf16 casts ----------------
#define N4_X  (MM*KK/4)
#define N4_WQ (NQKV*KK/4)
#define N4_WO (D_MODEL*D_MODEL/4)
__global__ void cast3_kernel(const float* __restrict__ x, const float* __restrict__ wq,
                             const float* __restrict__ wo,
                             unsigned short* __restrict__ xb, unsigned short* __restrict__ wqb,
                             unsigned short* __restrict__ wob){
    int i = blockIdx.x * blockDim.x + threadIdx.x;
    const float* src; unsigned short* dst; int j;
    if (i < N4_X)              { src = x;  dst = xb;  j = i; }
    else if (i < N4_X + N4_WQ) { src = wq; dst = wqb; j = i - N4_X; }
    else                       { src = wo; dst = wob; j = i - N4_X - N4_WQ; }
    float4 v = reinterpret_cast<const float4*>(src)[j];
    ushort4 o;
    o.x = f2bf(v.x); o.y = f2bf(v.y); o.z = f2bf(v.z); o.w = f2bf(v.w);
    reinterpret_cast<ushort4*>(dst)[j] = o;
}

// ---------------- QKV projection GEMM (double-buffered 2-phase) ----------------
__global__ __launch_bounds__(256) void gemm_qkv(
    const unsigned short* __restrict__ A, const unsigned short* __restrict__ Bw,
    const float* __restrict__ bias,
    unsigned short* __restrict__ qb, unsigned short* __restrict__ kb,
    unsigned short* __restrict__ vtb)
{
    __shared__ alignas(16) unsigned short As[2][128*32];
    __shared__ alignas(16) unsigned short Bs[2][128*32];
    const int tiles_n = NQKV/128;                 // 24
    int nwg = gridDim.x;
    int orig = blockIdx.x;
    int bid = (orig & 7) * (nwg >> 3) + (orig >> 3);   // bijective: nwg%8==0
    int bm = (bid / tiles_n) * 128;
    int bn = (bid % tiles_n) * 128;
    int tid = threadIdx.x;
    int w = tid >> 6, l = tid & 63;
    int wr = (w >> 1) * 64, wc = (w & 1) * 64;
    int lr = l & 15, hi = l >> 4;

    f32x4 acc[4][4] = {};

    int srow = tid >> 2;            // 0..63
    int scol = (tid & 3) * 8;       // ushort offset
    const unsigned short* Ap = A + (size_t)(bm + srow) * KK + scol;
    const unsigned short* Bp = Bw + (size_t)(bn + srow) * KK + scol;

    {
        char* AsB = (char*)&As[0][0] + w*1024;
        char* BsB = (char*)&Bs[0][0] + w*1024;
        gload_lds16(Ap,           AsB);
        gload_lds16(Ap + 64*KK,   AsB + 4096);
        gload_lds16(Bp,           BsB);
        gload_lds16(Bp + 64*KK,   BsB + 4096);
    }
    __syncthreads();

    int cur = 0;
    for (int k0 = 0; k0 < KK; k0 += 32) {
        if (k0 + 32 < KK) {
            char* AsB = (cur ? (char*)&As[0][0] : (char*)&As[1][0]) + w*1024;
            char* BsB = (cur ? (char*)&Bs[0][0] : (char*)&Bs[1][0]) + w*1024;
            gload_lds16(Ap + k0 + 32,          AsB);
            gload_lds16(Ap + 64*KK + k0 + 32,  AsB + 4096);
            gload_lds16(Bp + k0 + 32,          BsB);
            gload_lds16(Bp + 64*KK + k0 + 32,  BsB + 4096);
        }
        const unsigned short* Ab = cur ? &As[1][0] : &As[0][0];
        const unsigned short* Bb = cur ? &Bs[1][0] : &Bs[0][0];
        bf16x8 af[4], bfr[4];
        #pragma unroll
        for (int m = 0; m < 4; m++)
            af[m] = *reinterpret_cast<const bf16x8*>(&Ab[(wr + m*16 + lr)*32 + hi*8]);
        #pragma unroll
        for (int n = 0; n < 4; n++)
            bfr[n] = *reinterpret_cast<const bf16x8*>(&Bb[(wc + n*16 + lr)*32 + hi*8]);
        #pragma unroll
        for (int m = 0; m < 4; m++)
            #pragma unroll
            for (int n = 0; n < 4; n++)
                acc[m][n] = __builtin_amdgcn_mfma_f32_16x16x32_bf16(af[m], bfr[n], acc[m][n], 0, 0, 0);
        __syncthreads();
        cur ^= 1;
    }

    #pragma unroll
    for (int m = 0; m < 4; m++) {
        int gm = bm + wr + m*16 + hi*4;       // +r
        int b  = gm >> 11;
        int t  = gm & 2047;
        #pragma unroll
        for (int n = 0; n < 4; n++) {
            int gn = bn + wc + n*16 + lr;
            float bv = bias[gn];
            int sec = gn >> 10;               // 0=Q 1=K 2=V
            int nn  = gn & 1023;
            int h = nn >> 6, d = nn & 63;
            int bh = b * NHEADS + h;
            if (sec == 2) {
                ushort4 pk;
                pk.x = f2bf(acc[m][n][0] + bv);
                pk.y = f2bf(acc[m][n][1] + bv);
                pk.z = f2bf(acc[m][n][2] + bv);
                pk.w = f2bf(acc[m][n][3] + bv);
                *reinterpret_cast<ushort4*>(&vtb[((size_t)bh*HD + d)*TT + t]) = pk;
            } else {
                unsigned short* dst = (sec == 0) ? qb : kb;
                #pragma unroll
                for (int r = 0; r < 4; r++)
                    dst[((size_t)bh*TT + t + r)*HD + d] = f2bf(acc[m][n][r] + bv);
            }
        }
    }
}

// ---------------- causal flash attention v4: paired k-tiles ----------------
// grid (bh, 16); 8 waves; Q tile 128 rows, wave w owns rows [w*16,+16)
// Swapped QK^T: s = mfma(K, Q) -> lane (lr,hi) holds S[k=kb+n*16+hi*4+r][q=qrow+lr]
// Two 64-k tiles per barrier (4 K/V LDS slots), merged softmax bookkeeping.
__global__ __launch_bounds__(512) void attn_kernel(
    const unsigned short* __restrict__ qb, const unsigned short* __restrict__ kb,
    const unsigned short* __restrict__ vtb, unsigned short* __restrict__ ao)
{
    __shared__ alignas(16) unsigned short Kt[4][64*64];
    __shared__ alignas(16) unsigned short Vt[4][64*64];
    __shared__ alignas(16) unsigned short Pl[8][16*64];

    const int bh = blockIdx.x;
    const int qt = (gridDim.y - 1) - blockIdx.y;   // big tiles first
    const int tid = threadIdx.x;
    const int w = tid >> 6, l = tid & 63;
    const int lr = l & 15, hi = l >> 4;

    const int qbase = qt * 128;
    const int qrow  = qbase + w*16;
    const int npairs = qt + 1;                     // tiles 0..2qt+1, always even count

    const unsigned short* Qp = qb + ((size_t)bh*TT + qrow) * HD;
    bf16x8 qf0 = *reinterpret_cast<const bf16x8*>(Qp + lr*HD + hi*8);
    bf16x8 qf1 = *reinterpret_cast<const bf16x8*>(Qp + lr*HD + 32 + hi*8);

    const unsigned short* Kg = kb  + (size_t)bh*TT*HD;
    const unsigned short* Vg = vtb + (size_t)bh*HD*TT;

    // staging: wave w loads rows [w*8,+8) of each 64-row tile.
    // LDS[row][c16] == G[row][c16 ^ (row&7)]
    const int srow = w*8 + (l >> 3);
    const int sc16 = (l & 7) ^ (srow & 7);
    char* KS0 = (char*)&Kt[0][0] + w*1024;  char* KS1 = (char*)&Kt[1][0] + w*1024;
    char* KS2 = (char*)&Kt[2][0] + w*1024;  char* KS3 = (char*)&Kt[3][0] + w*1024;
    char* VS0 = (char*)&Vt[0][0] + w*1024;  char* VS1 = (char*)&Vt[1][0] + w*1024;
    char* VS2 = (char*)&Vt[2][0] + w*1024;  char* VS3 = (char*)&Vt[3][0] + w*1024;

    // prologue: stage tiles 0,1 into slots 0,1
    gload_lds16(Kg + (size_t)srow*HD + sc16*8,        KS0);
    gload_lds16(Vg + (size_t)srow*TT + sc16*8,        VS0);
    gload_lds16(Kg + (size_t)(64 + srow)*HD + sc16*8, KS1);
    gload_lds16(Vg + (size_t)srow*TT + 64 + sc16*8,   VS1);
    __syncthreads();

    float mS = -3e38f, lS = 0.f;
    f32x4 o[4] = {};
    const float sc = 0.125f * 1.4426950408889634f;   // 1/sqrt(64) * log2(e)
    const float THR = 8.0f / sc;
    const int qg = qrow + lr;
    const int swp = (lr & 7) << 4;
    char* Pw = (char*)&Pl[w][0];

    for (int j = 0; j < npairs; ++j) {
        const int ph = j & 1;
        const char* Ka = ph ? (const char*)&Kt[2][0] : (const char*)&Kt[0][0];
        const char* Kc = ph ? (const char*)&Kt[3][0] : (const char*)&Kt[1][0];
        const char* Va = ph ? (const char*)&Vt[2][0] : (const char*)&Vt[0][0];
        const char* Vc = ph ? (const char*)&Vt[3][0] : (const char*)&Vt[1][0];
        if (j + 1 < npairs) {   // prefetch next pair into the other slot pair
            const int tn = 2*j + 2;
            char* kd0 = ph ? KS0 : KS2;  char* kd1 = ph ? KS1 : KS3;
            char* vd0 = ph ? VS0 : VS2;  char* vd1 = ph ? VS1 : VS3;
            gload_lds16(Kg + (size_t)(tn*64 + srow)*HD + sc16*8,      kd0);
            gload_lds16(Vg + (size_t)srow*TT + tn*64 + sc16*8,        vd0);
            gload_lds16(Kg + (size_t)(tn*64 + 64 + srow)*HD + sc16*8, kd1);
            gload_lds16(Vg + (size_t)srow*TT + tn*64 + 64 + sc16*8,   vd1);
        }
        const int kba = 2*j*64;
        const int kbb = kba + 64;
        const bool cb = (kbb <= qrow + 15);   // tile-a is always live

        f32x4 sa4[4] = {}, sb4[4] = {};
        __builtin_amdgcn_s_setprio(1);
        #pragma unroll
        for (int n = 0; n < 4; n++) {
            int rb = (n*16 + lr) * 128;
            bf16x8 k0 = *reinterpret_cast<const bf16x8*>(Ka + rb + (( 0 + hi*16) ^ swp));
            bf16x8 k1 = *reinterpret_cast<const bf16x8*>(Ka + rb + ((64 + hi*16) ^ swp));
            sa4[n] = __builtin_amdgcn_mfma_f32_16x16x32_bf16(k0, qf0, sa4[n], 0, 0, 0);
            sa4[n] = __builtin_amdgcn_mfma_f32_16x16x32_bf16(k1, qf1, sa4[n], 0, 0, 0);
        }
        if (cb) {
            #pragma unroll
            for (int n = 0; n < 4; n++) {
                int rb = (n*16 + lr) * 128;
                bf16x8 k0 = *reinterpret_cast<const bf16x8*>(Kc + rb + (( 0 + hi*16) ^ swp));
                bf16x8 k1 = *reinterpret_cast<const bf16x8*>(Kc + rb + ((64 + hi*16) ^ swp));
                sb4[n] = __builtin_amdgcn_mfma_f32_16x16x32_bf16(k0, qf0, sb4[n], 0, 0, 0);
                sb4[n] = __builtin_amdgcn_mfma_f32_16x16x32_bf16(k1, qf1, sb4[n], 0, 0, 0);
            }
        }
        __builtin_amdgcn_s_setprio(0);

        if (kba + 63 > qrow) {
            #pragma unroll
            for (int n = 0; n < 4; n++)
                #pragma unroll
                for (int r = 0; r < 4; r++)
                    if (kba + n*16 + hi*4 + r > qg) sa4[n][r] = -3e38f;
        }
        if (cb && kbb + 63 > qrow) {
            #pragma unroll
            for (int n = 0; n < 4; n++)
                #pragma unroll
                for (int r = 0; r < 4; r++)
                    if (kbb + n*16 + hi*4 + r > qg) sb4[n][r] = -3e38f;
        }

        // per-q-row max over the pair (in-lane tree + cross-hi)
        float t0 = fmaxf(fmaxf(sa4[0][0], sa4[0][1]), fmaxf(sa4[0][2], sa4[0][3]));
        float t1 = fmaxf(fmaxf(sa4[1][0], sa4[1][1]), fmaxf(sa4[1][2], sa4[1][3]));
        float t2 = fmaxf(fmaxf(sa4[2][0], sa4[2][1]), fmaxf(sa4[2][2], sa4[2][3]));
        float t3 = fmaxf(fmaxf(sa4[3][0], sa4[3][1]), fmaxf(sa4[3][2], sa4[3][3]));
        float rm = fmaxf(fmaxf(t0, t1), fmaxf(t2, t3));
        if (cb) {
            float u0 = fmaxf(fmaxf(sb4[0][0], sb4[0][1]), fmaxf(sb4[0][2], sb4[0][3]));
            float u1 = fmaxf(fmaxf(sb4[1][0], sb4[1][1]), fmaxf(sb4[1][2], sb4[1][3]));
            float u2 = fmaxf(fmaxf(sb4[2][0], sb4[2][1]), fmaxf(sb4[2][2], sb4[2][3]));
            float u3 = fmaxf(fmaxf(sb4[3][0], sb4[3][1]), fmaxf(sb4[3][2], sb4[3][3]));
            rm = fmaxf(rm, fmaxf(fmaxf(u0, u1), fmaxf(u2, u3)));
        }
        rm = fmaxf(rm, __shfl_xor(rm, 16, 64));
        rm = fmaxf(rm, __shfl_xor(rm, 32, 64));
        if (!__all(rm - mS <= THR)) {        // pair-merged defer-max rescale
            float newm = fmaxf(mS, rm);
            float al = exp2f(sc * (mS - newm));
            mS = newm;
            lS *= al;
            #pragma unroll
            for (int r = 0; r < 4; r++) {
                float alr = __shfl(al, hi*4 + r, 64);
                o[0][r] *= alr; o[1][r] *= alr; o[2][r] *= alr; o[3][r] *= alr;
            }
        }
        const float c0 = sc * mS;

        // tile-a: exp + pack + P-write; partial row-sum
        float rs = 0.f;
        #pragma unroll
        for (int n = 0; n < 4; n++) {
            float p0 = exp2f(fmaf(sa4[n][0], sc, -c0));
            float p1 = exp2f(fmaf(sa4[n][1], sc, -c0));
            float p2 = exp2f(fmaf(sa4[n][2], sc, -c0));
            float p3 = exp2f(fmaf(sa4[n][3], sc, -c0));
            rs += (p0 + p1) + (p2 + p3);
            ushort4 u;
            u.x = f2bf(p0); u.y = f2bf(p1); u.z = f2bf(p2); u.w = f2bf(p3);
            *reinterpret_cast<ushort4*>(Pw + (lr*128 + ((n*32 + hi*8) ^ swp))) = u;
        }
        // tile-b: exp + pack into registers (written after PV_a)
        ushort4 ub[4];
        if (cb) {
            #pragma unroll
            for (int n = 0; n < 4; n++) {
                float p0 = exp2f(fmaf(sb4[n][0], sc, -c0));
                float p1 = exp2f(fmaf(sb4[n][1], sc, -c0));
                float p2 = exp2f(fmaf(sb4[n][2], sc, -c0));
                float p3 = exp2f(fmaf(sb4[n][3], sc, -c0));
                rs += (p0 + p1) + (p2 + p3);
                ub[n].x = f2bf(p0); ub[n].y = f2bf(p1);
                ub[n].z = f2bf(p2); ub[n].w = f2bf(p3);
            }
        }
        rs += __shfl_xor(rs, 16, 64);
        rs += __shfl_xor(rs, 32, 64);
        lS += rs;

        // PV tile-a
        {
            bf16x8 pa0 = *reinterpret_cast<const bf16x8*>(Pw + (lr*128 + (( 0 + hi*16) ^ swp)));
            bf16x8 pa1 = *reinterpret_cast<const bf16x8*>(Pw + (lr*128 + ((64 + hi*16) ^ swp)));
            __builtin_amdgcn_s_setprio(1);
            #pragma unroll
            for (int nd = 0; nd < 4; nd++) {
                int rb = (nd*16 + lr) * 128;
                bf16x8 v0 = *reinterpret_cast<const bf16x8*>(Va + rb + (( 0 + hi*16) ^ swp));
                bf16x8 v1 = *reinterpret_cast<const bf16x8*>(Va + rb + ((64 + hi*16) ^ swp));
                o[nd] = __builtin_amdgcn_mfma_f32_16x16x32_bf16(pa0, v0, o[nd], 0, 0, 0);
                o[nd] = __builtin_amdgcn_mfma_f32_16x16x32_bf16(pa1, v1, o[nd], 0, 0, 0);
            }
            __builtin_amdgcn_s_setprio(0);
        }
        // PV tile-b
        if (cb) {
            #pragma unroll
            for (int n = 0; n < 4; n++)
                *reinterpret_cast<ushort4*>(Pw + (lr*128 + ((n*32 + hi*8) ^ swp))) = ub[n];
            bf16x8 pa0 = *reinterpret_cast<const bf16x8*>(Pw + (lr*128 + (( 0 + hi*16) ^ swp)));
            bf16x8 pa1 = *reinterpret_cast<const bf16x8*>(Pw + (lr*128 + ((64 + hi*16) ^ swp)));
            __builtin_amdgcn_s_setprio(1);
            #pragma unroll
            for (int nd = 0; nd < 4; nd++) {
                int rb = (nd*16 + lr) * 128;
                bf16x8 v0 = *reinterpret_cast<const bf16x8*>(Vc + rb + (( 0 + hi*16) ^ swp));
                bf16x8 v1 = *reinterpret_cast<const bf16x8*>(Vc + rb + ((64 + hi*16) ^ swp));
                o[nd] = __builtin_amdgcn_mfma_f32_16x16x32_bf16(pa0, v0, o[nd], 0, 0, 0);
                o[nd] = __builtin_amdgcn_mfma_f32_16x16x32_bf16(pa1, v1, o[nd], 0, 0, 0);
            }
            __builtin_amdgcn_s_setprio(0);
        }
        __syncthreads();
    }

    float inv = 1.0f / lS;
    int b = bh >> 4, h = bh & 15;
    #pragma unroll
    for (int r = 0; r < 4; r++) {
        float invr = __shfl(inv, hi*4 + r, 64);
        int t = qrow + hi*4 + r;
        #pragma unroll
        for (int nd = 0; nd < 4; nd++) {
            float val = o[nd][r] * invr;
            ao[((size_t)b*TT + t)*D_MODEL + h*HD + nd*16 + lr] = f2bf(val);
        }
    }
}

// ---------------- output projection GEMM (double-buffered 2-phase) ----------------
__global__ __launch_bounds__(256) void gemm_out(
    const unsigned short* __restrict__ A, const unsigned short* __restrict__ Bw,
    const float* __restrict__ bias, float* __restrict__ out)
{
    __shared__ alignas(16) unsigned short As[2][128*32];
    __shared__ alignas(16) unsigned short Bs[2][128*32];
    const int tiles_n = D_MODEL/128;              // 8
    int nwg = gridDim.x;
    int orig = blockIdx.x;
    int bid = (orig & 7) * (nwg >> 3) + (orig >> 3);
    int bm = (bid / tiles_n) * 128;
    int bn = (bid % tiles_n) * 128;
    int tid = threadIdx.x;
    int w = tid >> 6, l = tid & 63;
    int wr = (w >> 1) * 64, wc = (w & 1) * 64;
    int lr = l & 15, hi = l >> 4;

    f32x4 acc[4][4] = {};

    int srow = tid >> 2;
    int scol = (tid & 3) * 8;
    const unsigned short* Ap = A + (size_t)(bm + srow) * KK + scol;
    const unsigned short* Bp = Bw + (size_t)(bn + srow) * KK + scol;

    {
        char* AsB = (char*)&As[0][0] + w*1024;
        char* BsB = (char*)&Bs[0][0] + w*1024;
        gload_lds16(Ap,           AsB);
        gload_lds16(Ap + 64*KK,   AsB + 4096);
        gload_lds16(Bp,           BsB);
        gload_lds16(Bp + 64*KK,   BsB + 4096);
    }
    __syncthreads();

    int cur = 0;
    for (int k0 = 0; k0 < KK; k0 += 32) {
        if (k0 + 32 < KK) {
            char* AsB = (cur ? (char*)&As[0][0] : (char*)&As[1][0]) + w*1024;
            char* BsB = (cur ? (char*)&Bs[0][0] : (char*)&Bs[1][0]) + w*1024;
            gload_lds16(Ap + k0 + 32,          AsB);
            gload_lds16(Ap + 64*KK + k0 + 32,  AsB + 4096);
            gload_lds16(Bp + k0 + 32,          BsB);
            gload_lds16(Bp + 64*KK + k0 + 32,  BsB + 4096);
        }
        const unsigned short* Ab = cur ? &As[1][0] : &As[0][0];
        const unsigned short* Bb = cur ? &Bs[1][0] : &Bs[0][0];
        bf16x8 af[4], bfr[4];
        #pragma unroll
        for (int m = 0; m < 4; m++)
            af[m] = *reinterpret_cast<const bf16x8*>(&Ab[(wr + m*16 + lr)*32 + hi*8]);
        #pragma unroll
        for (int n = 0; n < 4; n++)
            bfr[n] = *reinterpret_cast<const bf16x8*>(&Bb[(wc + n*16 + lr)*32 + hi*8]);
        #pragma unroll
        for (int m = 0; m < 4; m++)
            #pragma unroll
            for (int n = 0; n < 4; n++)
                acc[m][n] = __builtin_amdgcn_mfma_f32_16x16x32_bf16(af[m], bfr[n], acc[m][n], 0, 0, 0);
        __syncthreads();
        cur ^= 1;
    }

    #pragma unroll
    for (int m = 0; m < 4; m++) {
        int gm = bm + wr + m*16 + hi*4;
        #pragma unroll
        for (int n = 0; n < 4; n++) {
            int gn = bn + wc + n*16 + lr;
            float bv = bias[gn];
            #pragma unroll
            for (int r = 0; r < 4; r++)
                out[(size_t)(gm + r)*D_MODEL + gn] = acc[m][n][r] + bv;
        }
    }
}

extern "C" void kernel_launch(void* const* d_in, const int* in_sizes, int n_in,
                              void* d_out, int out_size, void* d_ws, size_t ws_size,
                              hipStream_t stream) {
    const float* x     = (const float*)d_in[0];
    const float* w_qkv = (const float*)d_in[1];
    const float* b_qkv = (const float*)d_in[2];
    const float* w_out = (const float*)d_in[3];
    const float* b_out = (const float*)d_in[4];
    float* out = (float*)d_out;

    char* ws = (char*)d_ws;
    unsigned short* xbf   = (unsigned short*)(ws);                         // 16 MB
    unsigned short* wqkvb = (unsigned short*)(ws + (size_t)16777216);      // 6 MB
    unsigned short* woutb = (unsigned short*)(ws + (size_t)23068672);      // 2 MB
    unsigned short* qb    = (unsigned short*)(ws + (size_t)25165824);      // 16 MB
    unsigned short* kb    = (unsigned short*)(ws + (size_t)41943040);      // 16 MB
    unsigned short* vtb   = (unsigned short*)(ws + (size_t)58720256);      // 16 MB
    unsigned short* aob   = xbf;  // alias: x_bf16 dead after gemm_qkv

    cast3_kernel<<<(N4_X + N4_WQ + N4_WO)/256, 256, 0, stream>>>(x, w_qkv, w_out, xbf, wqkvb, woutb);

    gemm_qkv<<<(MM/128)*(NQKV/128), 256, 0, stream>>>(xbf, wqkvb, b_qkv, qb, kb, vtb);
    attn_kernel<<<dim3(BB*NHEADS, TT/128), 512, 0, stream>>>(qb, kb, vtb, aob);
    gemm_out<<<(MM/128)*(D_MODEL/128), 256, 0, stream>>>(aob, woutb, b_out, out);
}

// Round 5
// 166.720 us; speedup vs baseline: 2.1936x; 1.0673x over previous
//
#include <hip/hip_runtime.h>
#include <hip/hip_bf16.h>
#include <stdint.h>

#define D_MODEL 1024
#define NHEADS 16
#define HD 64
#define BB 4
#define TT 2048
#define MM (BB*TT)          // 8192 rows
#define NQKV (3*D_MODEL)    // 3072
#define KK D_MODEL          // 1024

typedef __attribute__((ext_vector_type(4))) float f32x4;
typedef __attribute__((ext_vector_type(8))) short bf16x8;

__device__ __forceinline__ unsigned short f2bf(float x){
    union { __hip_bfloat16 h; unsigned short u; } c;
    c.h = __float2bfloat16(x);
    return c.u;
}

__device__ __forceinline__ void gload_lds16(const void* g, void* l){
    __builtin_amdgcn_global_load_lds(
        (const __attribute__((address_space(1))) unsigned int*)g,
        (__attribute__((address_space(3))) unsigned int*)l,
        16, 0, 0);
}

// ---------------- fused fp32 -> bf16 casts ----------------
#define N4_X  (MM*KK/4)
#define N4_WQ (NQKV*KK/4)
#define N4_WO (D_MODEL*D_MODEL/4)
__global__ void cast3_kernel(const float* __restrict__ x, const float* __restrict__ wq,
                             const float* __restrict__ wo,
                             unsigned short* __restrict__ xb, unsigned short* __restrict__ wqb,
                             unsigned short* __restrict__ wob){
    int i = blockIdx.x * blockDim.x + threadIdx.x;
    const float* src; unsigned short* dst; int j;
    if (i < N4_X)              { src = x;  dst = xb;  j = i; }
    else if (i < N4_X + N4_WQ) { src = wq; dst = wqb; j = i - N4_X; }
    else                       { src = wo; dst = wob; j = i - N4_X - N4_WQ; }
    float4 v = reinterpret_cast<const float4*>(src)[j];
    ushort4 o;
    o.x = f2bf(v.x); o.y = f2bf(v.y); o.z = f2bf(v.z); o.w = f2bf(v.w);
    reinterpret_cast<ushort4*>(dst)[j] = o;
}

// ============ counted-vmcnt ring-3 GEMM core (BM=256, BN=128, BK=32) ============
// 512 threads = 8 waves (2 M x 4 N). Per-wave out 128x32 = acc[8][2].
// LDS ring of 3 K-tiles: As 256x32, Bs 128x32 bf16, XOR-swizzled (c16 ^= row&3).
// Phase t: vmcnt(3); s_barrier; ds_read frags(buf t%3); issue tile t+2 stage
// (buf (t+2)%3); 16 MFMA. Tail: t=30 vmcnt(3) no-issue, t=31 vmcnt(0).

#define GEMM_PROLOGUE(A_, B_)                                                   \
    const int tid = threadIdx.x;                                                \
    const int w = tid >> 6, l = tid & 63;                                       \
    const int wm = w >> 2, wn = w & 3;                                          \
    const int lr = l & 15, hi = l >> 4;                                         \
    f32x4 acc[8][2] = {};                                                       \
    const int c16 = hi ^ (lr & 3);                                              \
    const int base_a = (wm*128 + lr)*32 + c16*8;                                \
    const int base_b = (wn*32  + lr)*32 + c16*8;                                \
    const int g16 = ((tid & 3) ^ ((tid >> 2) & 3)) * 8;                         \
    const unsigned short* Aap = A_ + (size_t)(bm + (tid >> 2)) * KK + g16;      \
    const unsigned short* Bbp = B_ + (size_t)(bn + (tid >> 2)) * KK + g16;      \
    char* AsL = (char*)&As[0][0];                                               \
    char* BsL = (char*)&Bs[0][0];                                               \
    /* stage tiles 0,1 (order matters for vmcnt accounting) */                  \
    gload_lds16(Aap,                 AsL + tid*16);                             \
    gload_lds16(Aap + 128*KK,        AsL + 8192 + tid*16);                      \
    gload_lds16(Bbp,                 BsL + tid*16);                             \
    gload_lds16(Aap + 32,            AsL + 16384 + tid*16);                     \
    gload_lds16(Aap + 128*KK + 32,   AsL + 16384 + 8192 + tid*16);              \
    gload_lds16(Bbp + 32,            BsL + 8192 + tid*16);

#define GPHASE(VM, bc, bi, tnext, DOISSUE) do {                                 \
    asm volatile("s_waitcnt vmcnt(" #VM ")" ::: "memory");                      \
    __builtin_amdgcn_s_barrier();                                               \
    asm volatile("" ::: "memory");                                              \
    bf16x8 af[8], bfn[2];                                                       \
    _Pragma("unroll")                                                           \
    for (int m = 0; m < 8; m++)                                                 \
        af[m] = *reinterpret_cast<const bf16x8*>(&As[bc][base_a + m*512]);      \
    _Pragma("unroll")                                                           \
    for (int n = 0; n < 2; n++)                                                 \
        bfn[n] = *reinterpret_cast<const bf16x8*>(&Bs[bc][base_b + n*512]);     \
    if (DOISSUE) {                                                              \
        gload_lds16(Aap + (tnext)*32,           AsL + (bi)*16384 + tid*16);     \
        gload_lds16(Aap + 128*KK + (tnext)*32,  AsL + (bi)*16384 + 8192 + tid*16);\
        gload_lds16(Bbp + (tnext)*32,           BsL + (bi)*8192 + tid*16);      \
    }                                                                           \
    __builtin_amdgcn_s_setprio(1);                                              \
    _Pragma("unroll")                                                           \
    for (int m = 0; m < 8; m++) {                                               \
        acc[m][0] = __builtin_amdgcn_mfma_f32_16x16x32_bf16(af[m], bfn[0], acc[m][0], 0, 0, 0); \
        acc[m][1] = __builtin_amdgcn_mfma_f32_16x16x32_bf16(af[m], bfn[1], acc[m][1], 0, 0, 0); \
    }                                                                           \
    __builtin_amdgcn_s_setprio(0);                                              \
} while(0)

#define GEMM_MAINLOOP()                                                         \
    for (int t3 = 0; t3 < 30; t3 += 3) {                                        \
        GPHASE(3, 0, 2, t3+2, 1);                                               \
        GPHASE(3, 1, 0, t3+3, 1);                                               \
        GPHASE(3, 2, 1, t3+4, 1);                                               \
    }                                                                           \
    GPHASE(3, 0, 2, 0, 0);                                                      \
    GPHASE(0, 1, 2, 0, 0);

// ---------------- QKV projection GEMM ----------------
__global__ __launch_bounds__(512, 4) void gemm_qkv(
    const unsigned short* __restrict__ A, const unsigned short* __restrict__ Bw,
    const float* __restrict__ bias,
    unsigned short* __restrict__ qb, unsigned short* __restrict__ kb,
    unsigned short* __restrict__ vtb)
{
    __shared__ alignas(16) unsigned short As[3][256*32];
    __shared__ alignas(16) unsigned short Bs[3][128*32];
    const int tiles_n = NQKV/128;                 // 24
    int nwg = gridDim.x;
    int orig = blockIdx.x;
    int bid = (orig & 7) * (nwg >> 3) + (orig >> 3);
    int bm = (bid / tiles_n) * 256;
    int bn = (bid % tiles_n) * 128;

    GEMM_PROLOGUE(A, Bw)
    GEMM_MAINLOOP()

    // epilogue: row gm = bm + wm*128 + m*16 + hi*4 + r; col gn = bn + wn*32 + n*16 + lr
    #pragma unroll
    for (int m = 0; m < 8; m++) {
        int gm = bm + wm*128 + m*16 + hi*4;       // +r
        int b  = gm >> 11;
        int t  = gm & 2047;
        #pragma unroll
        for (int n = 0; n < 2; n++) {
            int gn = bn + wn*32 + n*16 + lr;
            float bv = bias[gn];
            int sec = gn >> 10;               // 0=Q 1=K 2=V
            int nn  = gn & 1023;
            int h = nn >> 6, d = nn & 63;
            int bh = b * NHEADS + h;
            if (sec == 2) {
                ushort4 pk;
                pk.x = f2bf(acc[m][n][0] + bv);
                pk.y = f2bf(acc[m][n][1] + bv);
                pk.z = f2bf(acc[m][n][2] + bv);
                pk.w = f2bf(acc[m][n][3] + bv);
                *reinterpret_cast<ushort4*>(&vtb[((size_t)bh*HD + d)*TT + t]) = pk;
            } else {
                unsigned short* dst = (sec == 0) ? qb : kb;
                #pragma unroll
                for (int r = 0; r < 4; r++)
                    dst[((size_t)bh*TT + t + r)*HD + d] = f2bf(acc[m][n][r] + bv);
            }
        }
    }
}

// ---------------- output projection GEMM ----------------
__global__ __launch_bounds__(512, 4) void gemm_out(
    const unsigned short* __restrict__ A, const unsigned short* __restrict__ Bw,
    const float* __restrict__ bias, float* __restrict__ out)
{
    __shared__ alignas(16) unsigned short As[3][256*32];
    __shared__ alignas(16) unsigned short Bs[3][128*32];
    const int tiles_n = D_MODEL/128;              // 8
    int nwg = gridDim.x;
    int orig = blockIdx.x;
    int bid = (orig & 7) * (nwg >> 3) + (orig >> 3);
    int bm = (bid / tiles_n) * 256;
    int bn = (bid % tiles_n) * 128;

    GEMM_PROLOGUE(A, Bw)
    GEMM_MAINLOOP()

    #pragma unroll
    for (int m = 0; m < 8; m++) {
        int gm = bm + wm*128 + m*16 + hi*4;
        #pragma unroll
        for (int n = 0; n < 2; n++) {
            int gn = bn + wn*32 + n*16 + lr;
            float bv = bias[gn];
            #pragma unroll
            for (int r = 0; r < 4; r++)
                out[(size_t)(gm + r)*D_MODEL + gn] = acc[m][n][r] + bv;
        }
    }
}

// ---------------- causal flash attention (unchanged from R4) ----------------
__global__ __launch_bounds__(512) void attn_kernel(
    const unsigned short* __restrict__ qb, const unsigned short* __restrict__ kb,
    const unsigned short* __restrict__ vtb, unsigned short* __restrict__ ao)
{
    __shared__ alignas(16) unsigned short Kt[4][64*64];
    __shared__ alignas(16) unsigned short Vt[4][64*64];
    __shared__ alignas(16) unsigned short Pl[8][16*64];

    const int bh = blockIdx.x;
    const int qt = (gridDim.y - 1) - blockIdx.y;   // big tiles first
    const int tid = threadIdx.x;
    const int w = tid >> 6, l = tid & 63;
    const int lr = l & 15, hi = l >> 4;

    const int qbase = qt * 128;
    const int qrow  = qbase + w*16;
    const int npairs = qt + 1;

    const unsigned short* Qp = qb + ((size_t)bh*TT + qrow) * HD;
    bf16x8 qf0 = *reinterpret_cast<const bf16x8*>(Qp + lr*HD + hi*8);
    bf16x8 qf1 = *reinterpret_cast<const bf16x8*>(Qp + lr*HD + 32 + hi*8);

    const unsigned short* Kg = kb  + (size_t)bh*TT*HD;
    const unsigned short* Vg = vtb + (size_t)bh*HD*TT;

    const int srow = w*8 + (l >> 3);
    const int sc16 = (l & 7) ^ (srow & 7);
    char* KS0 = (char*)&Kt[0][0] + w*1024;  char* KS1 = (char*)&Kt[1][0] + w*1024;
    char* KS2 = (char*)&Kt[2][0] + w*1024;  char* KS3 = (char*)&Kt[3][0] + w*1024;
    char* VS0 = (char*)&Vt[0][0] + w*1024;  char* VS1 = (char*)&Vt[1][0] + w*1024;
    char* VS2 = (char*)&Vt[2][0] + w*1024;  char* VS3 = (char*)&Vt[3][0] + w*1024;

    gload_lds16(Kg + (size_t)srow*HD + sc16*8,        KS0);
    gload_lds16(Vg + (size_t)srow*TT + sc16*8,        VS0);
    gload_lds16(Kg + (size_t)(64 + srow)*HD + sc16*8, KS1);
    gload_lds16(Vg + (size_t)srow*TT + 64 + sc16*8,   VS1);
    __syncthreads();

    float mS = -3e38f, lS = 0.f;
    f32x4 o[4] = {};
    const float sc = 0.125f * 1.4426950408889634f;
    const float THR = 8.0f / sc;
    const int qg = qrow + lr;
    const int swp = (lr & 7) << 4;
    char* Pw = (char*)&Pl[w][0];

    for (int j = 0; j < npairs; ++j) {
        const int ph = j & 1;
        const char* Ka = ph ? (const char*)&Kt[2][0] : (const char*)&Kt[0][0];
        const char* Kc = ph ? (const char*)&Kt[3][0] : (const char*)&Kt[1][0];
        const char* Va = ph ? (const char*)&Vt[2][0] : (const char*)&Vt[0][0];
        const char* Vc = ph ? (const char*)&Vt[3][0] : (const char*)&Vt[1][0];
        if (j + 1 < npairs) {
            const int tn = 2*j + 2;
            char* kd0 = ph ? KS0 : KS2;  char* kd1 = ph ? KS1 : KS3;
            char* vd0 = ph ? VS0 : VS2;  char* vd1 = ph ? VS1 : VS3;
            gload_lds16(Kg + (size_t)(tn*64 + srow)*HD + sc16*8,      kd0);
            gload_lds16(Vg + (size_t)srow*TT + tn*64 + sc16*8,        vd0);
            gload_lds16(Kg + (size_t)(tn*64 + 64 + srow)*HD + sc16*8, kd1);
            gload_lds16(Vg + (size_t)srow*TT + tn*64 + 64 + sc16*8,   vd1);
        }
        const int kba = 2*j*64;
        const int kbb = kba + 64;
        const bool cb = (kbb <= qrow + 15);

        f32x4 sa4[4] = {}, sb4[4] = {};
        __builtin_amdgcn_s_setprio(1);
        #pragma unroll
        for (int n = 0; n < 4; n++) {
            int rb = (n*16 + lr) * 128;
            bf16x8 k0 = *reinterpret_cast<const bf16x8*>(Ka + rb + (( 0 + hi*16) ^ swp));
            bf16x8 k1 = *reinterpret_cast<const bf16x8*>(Ka + rb + ((64 + hi*16) ^ swp));
            sa4[n] = __builtin_amdgcn_mfma_f32_16x16x32_bf16(k0, qf0, sa4[n], 0, 0, 0);
            sa4[n] = __builtin_amdgcn_mfma_f32_16x16x32_bf16(k1, qf1, sa4[n], 0, 0, 0);
        }
        if (cb) {
            #pragma unroll
            for (int n = 0; n < 4; n++) {
                int rb = (n*16 + lr) * 128;
                bf16x8 k0 = *reinterpret_cast<const bf16x8*>(Kc + rb + (( 0 + hi*16) ^ swp));
                bf16x8 k1 = *reinterpret_cast<const bf16x8*>(Kc + rb + ((64 + hi*16) ^ swp));
                sb4[n] = __builtin_amdgcn_mfma_f32_16x16x32_bf16(k0, qf0, sb4[n], 0, 0, 0);
                sb4[n] = __builtin_amdgcn_mfma_f32_16x16x32_bf16(k1, qf1, sb4[n], 0, 0, 0);
            }
        }
        __builtin_amdgcn_s_setprio(0);

        if (kba + 63 > qrow) {
            #pragma unroll
            for (int n = 0; n < 4; n++)
                #pragma unroll
                for (int r = 0; r < 4; r++)
                    if (kba + n*16 + hi*4 + r > qg) sa4[n][r] = -3e38f;
        }
        if (cb && kbb + 63 > qrow) {
            #pragma unroll
            for (int n = 0; n < 4; n++)
                #pragma unroll
                for (int r = 0; r < 4; r++)
                    if (kbb + n*16 + hi*4 + r > qg) sb4[n][r] = -3e38f;
        }

        float t0 = fmaxf(fmaxf(sa4[0][0], sa4[0][1]), fmaxf(sa4[0][2], sa4[0][3]));
        float t1 = fmaxf(fmaxf(sa4[1][0], sa4[1][1]), fmaxf(sa4[1][2], sa4[1][3]));
        float t2 = fmaxf(fmaxf(sa4[2][0], sa4[2][1]), fmaxf(sa4[2][2], sa4[2][3]));
        float t3 = fmaxf(fmaxf(sa4[3][0], sa4[3][1]), fmaxf(sa4[3][2], sa4[3][3]));
        float rm = fmaxf(fmaxf(t0, t1), fmaxf(t2, t3));
        if (cb) {
            float u0 = fmaxf(fmaxf(sb4[0][0], sb4[0][1]), fmaxf(sb4[0][2], sb4[0][3]));
            float u1 = fmaxf(fmaxf(sb4[1][0], sb4[1][1]), fmaxf(sb4[1][2], sb4[1][3]));
            float u2 = fmaxf(fmaxf(sb4[2][0], sb4[2][1]), fmaxf(sb4[2][2], sb4[2][3]));
            float u3 = fmaxf(fmaxf(sb4[3][0], sb4[3][1]), fmaxf(sb4[3][2], sb4[3][3]));
            rm = fmaxf(rm, fmaxf(fmaxf(u0, u1), fmaxf(u2, u3)));
        }
        rm = fmaxf(rm, __shfl_xor(rm, 16, 64));
        rm = fmaxf(rm, __shfl_xor(rm, 32, 64));
        if (!__all(rm - mS <= THR)) {
            float newm = fmaxf(mS, rm);
            float al = exp2f(sc * (mS - newm));
            mS = newm;
            lS *= al;
            #pragma unroll
            for (int r = 0; r < 4; r++) {
                float alr = __shfl(al, hi*4 + r, 64);
                o[0][r] *= alr; o[1][r] *= alr; o[2][r] *= alr; o[3][r] *= alr;
            }
        }
        const float c0 = sc * mS;

        float rs = 0.f;
        #pragma unroll
        for (int n = 0; n < 4; n++) {
            float p0 = exp2f(fmaf(sa4[n][0], sc, -c0));
            float p1 = exp2f(fmaf(sa4[n][1], sc, -c0));
            float p2 = exp2f(fmaf(sa4[n][2], sc, -c0));
            float p3 = exp2f(fmaf(sa4[n][3], sc, -c0));
            rs += (p0 + p1) + (p2 + p3);
            ushort4 u;
            u.x = f2bf(p0); u.y = f2bf(p1); u.z = f2bf(p2); u.w = f2bf(p3);
            *reinterpret_cast<ushort4*>(Pw + (lr*128 + ((n*32 + hi*8) ^ swp))) = u;
        }
        ushort4 ub[4];
        if (cb) {
            #pragma unroll
            for (int n = 0; n < 4; n++) {
                float p0 = exp2f(fmaf(sb4[n][0], sc, -c0));
                float p1 = exp2f(fmaf(sb4[n][1], sc, -c0));
                float p2 = exp2f(fmaf(sb4[n][2], sc, -c0));
                float p3 = exp2f(fmaf(sb4[n][3], sc, -c0));
                rs += (p0 + p1) + (p2 + p3);
                ub[n].x = f2bf(p0); ub[n].y = f2bf(p1);
                ub[n].z = f2bf(p2); ub[n].w = f2bf(p3);
            }
        }
        rs += __shfl_xor(rs, 16, 64);
        rs += __shfl_xor(rs, 32, 64);
        lS += rs;

        {
            bf16x8 pa0 = *reinterpret_cast<const bf16x8*>(Pw + (lr*128 + (( 0 + hi*16) ^ swp)));
            bf16x8 pa1 = *reinterpret_cast<const bf16x8*>(Pw + (lr*128 + ((64 + hi*16) ^ swp)));
            __builtin_amdgcn_s_setprio(1);
            #pragma unroll
            for (int nd = 0; nd < 4; nd++) {
                int rb = (nd*16 + lr) * 128;
                bf16x8 v0 = *reinterpret_cast<const bf16x8*>(Va + rb + (( 0 + hi*16) ^ swp));
                bf16x8 v1 = *reinterpret_cast<const bf16x8*>(Va + rb + ((64 + hi*16) ^ swp));
                o[nd] = __builtin_amdgcn_mfma_f32_16x16x32_bf16(pa0, v0, o[nd], 0, 0, 0);
                o[nd] = __builtin_amdgcn_mfma_f32_16x16x32_bf16(pa1, v1, o[nd], 0, 0, 0);
            }
            __builtin_amdgcn_s_setprio(0);
        }
        if (cb) {
            #pragma unroll
            for (int n = 0; n < 4; n++)
                *reinterpret_cast<ushort4*>(Pw + (lr*128 + ((n*32 + hi*8) ^ swp))) = ub[n];
            bf16x8 pa0 = *reinterpret_cast<const bf16x8*>(Pw + (lr*128 + (( 0 + hi*16) ^ swp)));
            bf16x8 pa1 = *reinterpret_cast<const bf16x8*>(Pw + (lr*128 + ((64 + hi*16) ^ swp)));
            __builtin_amdgcn_s_setprio(1);
            #pragma unroll
            for (int nd = 0; nd < 4; nd++) {
                int rb = (nd*16 + lr) * 128;
                bf16x8 v0 = *reinterpret_cast<const bf16x8*>(Vc + rb + (( 0 + hi*16) ^ swp));
                bf16x8 v1 = *reinterpret_cast<const bf16x8*>(Vc + rb + ((64 + hi*16) ^ swp));
                o[nd] = __builtin_amdgcn_mfma_f32_16x16x32_bf16(pa0, v0, o[nd], 0, 0, 0);
                o[nd] = __builtin_amdgcn_mfma_f32_16x16x32_bf16(pa1, v1, o[nd], 0, 0, 0);
            }
            __builtin_amdgcn_s_setprio(0);
        }
        __syncthreads();
    }

    float inv = 1.0f / lS;
    int b = bh >> 4, h = bh & 15;
    #pragma unroll
    for (int r = 0; r < 4; r++) {
        float invr = __shfl(inv, hi*4 + r, 64);
        int t = qrow + hi*4 + r;
        #pragma unroll
        for (int nd = 0; nd < 4; nd++) {
            float val = o[nd][r] * invr;
            ao[((size_t)b*TT + t)*D_MODEL + h*HD + nd*16 + lr] = f2bf(val);
        }
    }
}

extern "C" void kernel_launch(void* const* d_in, const int* in_sizes, int n_in,
                              void* d_out, int out_size, void* d_ws, size_t ws_size,
                              hipStream_t stream) {
    const float* x     = (const float*)d_in[0];
    const float* w_qkv = (const float*)d_in[1];
    const float* b_qkv = (const float*)d_in[2];
    const float* w_out = (const float*)d_in[3];
    const float* b_out = (const float*)d_in[4];
    float* out = (float*)d_out;

    char* ws = (char*)d_ws;
    unsigned short* xbf   = (unsigned short*)(ws);                         // 16 MB
    unsigned short* wqkvb = (unsigned short*)(ws + (size_t)16777216);      // 6 MB
    unsigned short* woutb = (unsigned short*)(ws + (size_t)23068672);      // 2 MB
    unsigned short* qb    = (unsigned short*)(ws + (size_t)25165824);      // 16 MB
    unsigned short* kb    = (unsigned short*)(ws + (size_t)41943040);      // 16 MB
    unsigned short* vtb   = (unsigned short*)(ws + (size_t)58720256);      // 16 MB
    unsigned short* aob   = xbf;  // alias: x_bf16 dead after gemm_qkv

    cast3_kernel<<<(N4_X + N4_WQ + N4_WO)/256, 256, 0, stream>>>(x, w_qkv, w_out, xbf, wqkvb, woutb);

    gemm_qkv<<<(MM/256)*(NQKV/128), 512, 0, stream>>>(xbf, wqkvb, b_qkv, qb, kb, vtb);
    attn_kernel<<<dim3(BB*NHEADS, TT/128), 512, 0, stream>>>(qb, kb, vtb, aob);
    gemm_out<<<(MM/256)*(D_MODEL/128), 512, 0, stream>>>(aob, woutb, b_out, out);
}